// Round 4
// baseline (770.137 us; speedup 1.0000x reference)
//
#include <hip/hip_runtime.h>

typedef __attribute__((ext_vector_type(8))) short bf16x8;
typedef __attribute__((ext_vector_type(4))) float f32x4;
typedef __attribute__((ext_vector_type(8))) unsigned short u16x8;

__device__ __forceinline__ float bf2f(short s) {
  unsigned u = ((unsigned)(unsigned short)s) << 16;
  return __builtin_bit_cast(float, u);
}
__device__ __forceinline__ unsigned short f2bf(float f) {
  unsigned u = __builtin_bit_cast(unsigned, f);
  u = (u + 0x7fffu + ((u >> 16) & 1u)) >> 16;
  return (unsigned short)u;
}
__device__ __forceinline__ void gload16(const unsigned short* g, unsigned short* l) {
  __builtin_amdgcn_global_load_lds(
      (const __attribute__((address_space(1))) void*)g,
      (__attribute__((address_space(3))) void*)l, 16, 0, 0);
}

// ---------------- merged prep: input cvt + all 5 weight transposes ----------------
__global__ __launch_bounds__(256)
void prep_kernel(const float* __restrict__ input, const float* __restrict__ W1,
                 const float* __restrict__ W2, const float* __restrict__ Won1,
                 const float* __restrict__ Wc1,
                 unsigned short* __restrict__ inputb, unsigned short* __restrict__ W1T,
                 unsigned short* __restrict__ W2T, unsigned short* __restrict__ WcatT,
                 unsigned short* __restrict__ Wc1T) {
  int bid = blockIdx.x;
  const int t = threadIdx.x;
  if (bid < 2048) {  // cvt input -> bf16 (4096x1024)
    long i = ((long)bid * 256 + t) * 8;
    float4 a = *(const float4*)(input + i);
    float4 b = *(const float4*)(input + i + 4);
    u16x8 o;
    o[0] = f2bf(a.x); o[1] = f2bf(a.y); o[2] = f2bf(a.z); o[3] = f2bf(a.w);
    o[4] = f2bf(b.x); o[5] = f2bf(b.y); o[6] = f2bf(b.z); o[7] = f2bf(b.w);
    *(u16x8*)(inputb + i) = o;
    return;
  }
  bid -= 2048;
  const float* src; unsigned short* dst;
  int R, C, tilesX, tilesY; long sb, db;
  if (bid < 16384) {                    // W1[k][1024,2048] -> W1T[k][2048,1024]
    src = W1; dst = W1T; R = 1024; C = 2048; tilesX = 64; tilesY = 32;
    sb = 2097152; db = 2097152;
  } else if ((bid -= 16384) < 4096) {   // W2[k][2048,256] -> W2T[k][256,2048]
    src = W2; dst = W2T; R = 2048; C = 256; tilesX = 8; tilesY = 64;
    sb = 524288; db = 524288;
  } else if ((bid -= 4096) < 512) {     // Won1 top half -> WcatT[0:2048]
    src = Won1; dst = WcatT; R = 256; C = 2048; tilesX = 64; tilesY = 8;
    sb = 0; db = 0;
  } else if ((bid -= 512) < 512) {      // Won1 bottom half -> WcatT[2048:4096]
    src = Won1 + 524288; dst = WcatT + (long)2048 * 256;
    R = 256; C = 2048; tilesX = 64; tilesY = 8; sb = 0; db = 0;
  } else {                              // Wc1 -> Wc1T[2048,256]
    bid -= 512;
    src = Wc1; dst = Wc1T; R = 256; C = 2048; tilesX = 64; tilesY = 8;
    sb = 0; db = 0;
  }
  const int x = bid % tilesX;
  const int rem = bid / tilesX;
  const int y = rem % tilesY;
  const int z = rem / tilesY;
  src += (long)z * sb;
  dst += (long)z * db;
  __shared__ float tile[32][33];
  const int tx = t & 31, ty = t >> 5;
  const int bx = x * 32, by = y * 32;
  #pragma unroll
  for (int i = ty; i < 32; i += 8)
    tile[i][tx] = src[(long)(by + i) * C + bx + tx];
  __syncthreads();
  #pragma unroll
  for (int i = ty; i < 32; i += 8)
    dst[(long)(bx + i) * R + by + tx] = f2bf(tile[tx][i]);
}

// ---------------- bf16 MFMA GEMM: C[M,N] = A[M,K] @ Bt[N,K]^T ----------------
// m97 structure: 128x128 tile, BK=64, 4 waves (2x2), global_load_lds staging,
// linear LDS, 2-barrier loop. 1D grid, bijective XCD-chunked swizzle with
// GROUP_M supergrouping for per-XCD L2 locality.
template<bool HAS_BIAS, bool RELU>
__global__ __launch_bounds__(256, 2)
void gemm_bf16(const unsigned short* __restrict__ A,
               const unsigned short* __restrict__ Bt,
               const float* __restrict__ bias,
               unsigned short* __restrict__ C,
               int N, int K, int nx, int ny, int GM,
               long sA, long sB, long sBias, long sC) {
  __shared__ unsigned short As[128 * 64];
  __shared__ unsigned short Bs[128 * 64];
  const int t = threadIdx.x;
  const int lane = t & 63;
  const int w = t >> 6, wr = w >> 1, wc = w & 1;

  const int nwg = gridDim.x;
  const int cpx = nwg >> 3;
  const int id = blockIdx.x;
  const int sw = (id & 7) * cpx + (id >> 3);
  const int z = sw / (nx * ny);
  const int rem = sw % (nx * ny);
  const int band = rem / (GM * nx);
  const int r = rem % (GM * nx);
  const int y = band * GM + (r % GM);
  const int x = r / GM;
  const int m0 = y * 128, n0 = x * 128;

  A += (long)z * sA;
  Bt += (long)z * sB;
  C += (long)z * sC;

  const int po = w * 4;
  const int prow = lane >> 3;
  const int pcol = (lane & 7) * 8;

  f32x4 acc[4][4] = {};

  for (int kt = 0; kt < K; kt += 64) {
    __syncthreads();
    #pragma unroll
    for (int p = 0; p < 4; ++p) {
      const int q = po + p;
      const int row = q * 8 + prow;
      gload16(A + (long)(m0 + row) * K + kt + pcol, As + q * 512);
      gload16(Bt + (long)(n0 + row) * K + kt + pcol, Bs + q * 512);
    }
    __syncthreads();
    #pragma unroll
    for (int ks = 0; ks < 2; ++ks) {
      bf16x8 af[4], bfr[4];
      #pragma unroll
      for (int mi = 0; mi < 4; ++mi) {
        const int row = wr * 64 + mi * 16 + (lane & 15);
        af[mi] = *(const bf16x8*)((const char*)As + row * 128 + ks * 64 + (lane >> 4) * 16);
      }
      #pragma unroll
      for (int ni = 0; ni < 4; ++ni) {
        const int row = wc * 64 + ni * 16 + (lane & 15);
        bfr[ni] = *(const bf16x8*)((const char*)Bs + row * 128 + ks * 64 + (lane >> 4) * 16);
      }
      #pragma unroll
      for (int mi = 0; mi < 4; ++mi)
        #pragma unroll
        for (int ni = 0; ni < 4; ++ni)
          acc[mi][ni] = __builtin_amdgcn_mfma_f32_16x16x32_bf16(af[mi], bfr[ni], acc[mi][ni], 0, 0, 0);
    }
  }

  #pragma unroll
  for (int mi = 0; mi < 4; ++mi) {
    #pragma unroll
    for (int ni = 0; ni < 4; ++ni) {
      const int colg = n0 + wc * 64 + ni * 16 + (lane & 15);
      float bv = 0.f;
      if (HAS_BIAS) bv = bias[(long)z * sBias + colg];
      #pragma unroll
      for (int r2 = 0; r2 < 4; ++r2) {
        const int rowg = m0 + wr * 64 + mi * 16 + (lane >> 4) * 4 + r2;
        float v = acc[mi][ni][r2] + bv;
        if (RELU) v = fmaxf(v, 0.f);
        C[(long)rowg * N + colg] = f2bf(v);
      }
    }
  }
}

// ---------------- G3 special: C[M,4096] = A[M,256] @ Bt[4096,256]^T ----------------
// K=256 fits whole in LDS: stage A panel (128x256, 64KB) once via pre-swizzled
// global_load_lds (XOR swizzle kills the stride-512B 16-way bank conflict on
// fragment reads); B fragments load direct from L2 (WcatT L2-resident).
// One barrier, no K-loop, 2 blocks/CU.
__global__ __launch_bounds__(256, 2)
void gemm_k256(const unsigned short* __restrict__ A,
               const unsigned short* __restrict__ Bt,
               unsigned short* __restrict__ C,
               int nx, int ny, int GM, long sA, long sC) {
  __shared__ unsigned short As[128 * 256];  // 64KB
  const int t = threadIdx.x;
  const int lane = t & 63;
  const int w = t >> 6, wr = w >> 1, wc = w & 1;

  const int nwg = gridDim.x;
  const int cpx = nwg >> 3;
  const int id = blockIdx.x;
  const int sw = (id & 7) * cpx + (id >> 3);
  const int z = sw / (nx * ny);
  const int rem = sw % (nx * ny);
  const int band = rem / (GM * nx);
  const int r = rem % (GM * nx);
  const int y = band * GM + (r % GM);
  const int x = r / GM;
  const int m0 = y * 128, n0 = x * 128;

  A += (long)z * sA;
  C += (long)z * sC;

  // stage A: LDS[x_lin] = global[swz(x_lin)], swz(x) = x ^ (((x>>9)&7)<<4)
  #pragma unroll
  for (int p = 0; p < 16; ++p) {
    const int xb = (p * 4 + w) * 1024 + lane * 16;     // linear LDS byte pos
    const int xs = xb ^ (((xb >> 9) & 7) << 4);        // source logical byte
    const int row = xs >> 9;
    const int gb = xs & 511;
    gload16(A + (long)(m0 + row) * 256 + (gb >> 1), As + (p * 4 + w) * 512);
  }
  __syncthreads();

  f32x4 acc[4][4] = {};
  #pragma unroll
  for (int ks = 0; ks < 8; ++ks) {
    bf16x8 af[4], bfr[4];
    #pragma unroll
    for (int mi = 0; mi < 4; ++mi) {
      const int row = wr * 64 + mi * 16 + (lane & 15);
      const int colb = ks * 64 + (lane >> 4) * 16;
      af[mi] = *(const bf16x8*)((const char*)As + row * 512 + (colb ^ ((row & 7) << 4)));
    }
    #pragma unroll
    for (int ni = 0; ni < 4; ++ni) {
      const int brow = n0 + wc * 64 + ni * 16 + (lane & 15);
      bfr[ni] = *(const bf16x8*)(Bt + (long)brow * 256 + ks * 32 + (lane >> 4) * 8);
    }
    #pragma unroll
    for (int mi = 0; mi < 4; ++mi)
      #pragma unroll
      for (int ni = 0; ni < 4; ++ni)
        acc[mi][ni] = __builtin_amdgcn_mfma_f32_16x16x32_bf16(af[mi], bfr[ni], acc[mi][ni], 0, 0, 0);
  }

  #pragma unroll
  for (int mi = 0; mi < 4; ++mi) {
    #pragma unroll
    for (int ni = 0; ni < 4; ++ni) {
      const int colg = n0 + wc * 64 + ni * 16 + (lane & 15);
      #pragma unroll
      for (int r2 = 0; r2 < 4; ++r2) {
        const int rowg = m0 + wr * 64 + mi * 16 + (lane >> 4) * 4 + r2;
        C[(long)rowg * 4096 + colg] = f2bf(acc[mi][ni][r2]);
      }
    }
  }
}

// ---------------- fused clear heads: clear[k,b] = Wc2 . relu(emb @ Wc1 + bc1) ----------------
__global__ __launch_bounds__(256, 2)
void clear_fused(const unsigned short* __restrict__ emb,   // [8][Mc][256]
                 const unsigned short* __restrict__ Wc1T,  // [2048][256]
                 const float* __restrict__ bc1, const float* __restrict__ Wc2,
                 const float* __restrict__ bc2,
                 float* __restrict__ out, int Mc) {
  __shared__ unsigned short Ae[128 * 256];  // 64KB, XOR-swizzled rows of 512B
  __shared__ unsigned short Bs[128 * 64];   // 16KB linear
  __shared__ float red[2][128];
  const int t = threadIdx.x;
  const int lane = t & 63;
  const int w = t >> 6, wr = w >> 1, wc = w & 1;
  const int k = blockIdx.y;
  const int m0 = blockIdx.x * 128;
  const unsigned short* A = emb + ((long)k * Mc + m0) * 256;

  {
    const int srow = t >> 5;
    const int sc = t & 31;
    #pragma unroll
    for (int pass = 0; pass < 16; ++pass) {
      const int row = pass * 8 + srow;
      float4 v = *(const float4*)(A + (long)row * 256 + sc * 8);
      *(float4*)((char*)Ae + row * 512 + ((sc * 16) ^ ((row & 7) << 4))) = v;
    }
  }

  const int po = w * 4;
  const int prow = lane >> 3;
  const int pcol = (lane & 7) * 8;

  float rsum[4][4] = {};

  for (int nt = 0; nt < 16; ++nt) {
    f32x4 acc[4][4] = {};
    for (int kt = 0; kt < 256; kt += 64) {
      __syncthreads();
      #pragma unroll
      for (int p = 0; p < 4; ++p) {
        const int q = po + p;
        const int row = q * 8 + prow;
        gload16(Wc1T + (long)(nt * 128 + row) * 256 + kt + pcol, Bs + q * 512);
      }
      __syncthreads();
      #pragma unroll
      for (int ks = 0; ks < 2; ++ks) {
        bf16x8 af[4], bfr[4];
        #pragma unroll
        for (int mi = 0; mi < 4; ++mi) {
          const int row = wr * 64 + mi * 16 + (lane & 15);
          const int ce = kt + ks * 32 + (lane >> 4) * 8;
          af[mi] = *(const bf16x8*)((const char*)Ae + row * 512 + ((ce * 2) ^ ((row & 7) << 4)));
        }
        #pragma unroll
        for (int ni = 0; ni < 4; ++ni) {
          const int row = wc * 64 + ni * 16 + (lane & 15);
          bfr[ni] = *(const bf16x8*)((const char*)Bs + row * 128 + ks * 64 + (lane >> 4) * 16);
        }
        #pragma unroll
        for (int mi = 0; mi < 4; ++mi)
          #pragma unroll
          for (int ni = 0; ni < 4; ++ni)
            acc[mi][ni] = __builtin_amdgcn_mfma_f32_16x16x32_bf16(af[mi], bfr[ni], acc[mi][ni], 0, 0, 0);
      }
    }
    #pragma unroll
    for (int mi = 0; mi < 4; ++mi) {
      #pragma unroll
      for (int ni = 0; ni < 4; ++ni) {
        const int col = nt * 128 + wc * 64 + ni * 16 + (lane & 15);
        const float bv = bc1[col], wv = Wc2[col];
        #pragma unroll
        for (int r = 0; r < 4; ++r)
          rsum[mi][r] += fmaxf(acc[mi][ni][r] + bv, 0.f) * wv;
      }
    }
  }

  #pragma unroll
  for (int off = 1; off < 16; off <<= 1)
    #pragma unroll
    for (int mi = 0; mi < 4; ++mi)
      #pragma unroll
      for (int r = 0; r < 4; ++r)
        rsum[mi][r] += __shfl_xor(rsum[mi][r], off, 64);
  if ((lane & 15) == 0) {
    #pragma unroll
    for (int mi = 0; mi < 4; ++mi)
      #pragma unroll
      for (int r = 0; r < 4; ++r)
        red[wc][wr * 64 + mi * 16 + (lane >> 4) * 4 + r] = rsum[mi][r];
  }
  __syncthreads();
  if (t < 128)
    out[(long)(m0 + t) * 64 + 56 + k] = red[0][t] + red[1][t] + bc2[0];
}

// ---------------- pairwise reduce: on[p,b] ----------------
__global__ __launch_bounds__(256)
void pair_reduce_kernel(const unsigned short* __restrict__ UVT,  // [8][Mc][4096]
                        const float* __restrict__ bon1, const float* __restrict__ Won2,
                        const float* __restrict__ bon2,
                        float* __restrict__ out, int Mc) {
  __shared__ unsigned short uv[8 * 4096];
  const int b = blockIdx.x, t = threadIdx.x;
  const long kstride = (long)Mc * 4096;
  const unsigned short* src = UVT + (long)b * 4096;
  for (int k = 0; k < 8; ++k) {
    const unsigned short* s = src + (long)k * kstride;
    #pragma unroll
    for (int c0 = 0; c0 < 2; ++c0) {
      int c = c0 * 256 + t;
      int byte = k * 8192 + ((c * 16) ^ ((k & 7) << 4));
      *(float4*)((char*)uv + byte) = *(const float4*)(s + c * 8);
    }
  }
  __syncthreads();
  const int p = t & 63, q = t >> 6;
  float acc = 0.f;
  if (p < 56) {
    const int i = p / 7;
    const int jj = p % 7;
    const int j = jj + (jj >= i);
    const char* ubase = (const char*)uv + i * 8192;
    const char* vbase = (const char*)uv + j * 8192;
    const int uswz = (i & 7) << 4, vswz = (j & 7) << 4;
    for (int it = 0; it < 64; ++it) {
      const int h = q * 512 + it * 8;
      bf16x8 uu = *(const bf16x8*)(ubase + ((h * 2) ^ uswz));
      bf16x8 vv = *(const bf16x8*)(vbase + ((4096 + h * 2) ^ vswz));
      float4 ba = *(const float4*)(bon1 + h);
      float4 bb = *(const float4*)(bon1 + h + 4);
      float4 wa = *(const float4*)(Won2 + h);
      float4 wb = *(const float4*)(Won2 + h + 4);
      float bs[8] = {ba.x, ba.y, ba.z, ba.w, bb.x, bb.y, bb.z, bb.w};
      float wv[8] = {wa.x, wa.y, wa.z, wa.w, wb.x, wb.y, wb.z, wb.w};
      #pragma unroll
      for (int e = 0; e < 8; ++e) {
        float xv = bf2f(uu[e]) + bf2f(vv[e]) + bs[e];
        acc += fmaxf(xv, 0.f) * wv[e];
      }
    }
  }
  __syncthreads();
  float* red = (float*)uv;
  red[q * 64 + p] = acc;
  __syncthreads();
  if (t < 56)
    out[(long)b * 64 + t] = red[t] + red[64 + t] + red[128 + t] + red[192 + t] + bon2[0];
}

extern "C" void kernel_launch(void* const* d_in, const int* in_sizes, int n_in,
                              void* d_out, int out_size, void* d_ws, size_t ws_size,
                              hipStream_t stream) {
  (void)in_sizes; (void)n_in; (void)out_size;
  const float* input = (const float*)d_in[0];
  const float* W1    = (const float*)d_in[1];
  const float* b1    = (const float*)d_in[2];
  const float* W2    = (const float*)d_in[3];
  const float* b2    = (const float*)d_in[4];
  const float* Won1  = (const float*)d_in[5];
  const float* bon1  = (const float*)d_in[6];
  const float* Won2  = (const float*)d_in[7];
  const float* bon2  = (const float*)d_in[8];
  const float* Wc1   = (const float*)d_in[9];
  const float* bc1   = (const float*)d_in[10];
  const float* Wc2   = (const float*)d_in[11];
  const float* bc2   = (const float*)d_in[12];
  float* out = (float*)d_out;

  char* base = (char*)d_ws;
  unsigned short* inputb = (unsigned short*)(base);                  //  8 MB
  unsigned short* W1T    = (unsigned short*)(base + 8388608L);       // 32 MB [8][2048][1024]
  unsigned short* W2T    = (unsigned short*)(base + 41943040L);      //  8 MB [8][256][2048]
  unsigned short* WcatT  = (unsigned short*)(base + 50331648L);      //  2 MB [4096][256]
  unsigned short* Wc1T   = (unsigned short*)(base + 52428800L);      //  1 MB [2048][256]
  char* chunkbase = base + 53477376L;

  // per-chunk bytes = Mc * (32768 h + 4096 emb + 65536 UVT) = Mc * 102400
  int nc = 32;
  const int opts[6] = {1, 2, 4, 8, 16, 32};
  for (int oi = 0; oi < 6; ++oi) {
    long Mc_ = 4096 / opts[oi];
    if (53477376L + Mc_ * 102400L <= (long)ws_size) { nc = opts[oi]; break; }
  }
  const int Mc = 4096 / nc;
  unsigned short* hbuf   = (unsigned short*)chunkbase;
  unsigned short* embbuf = (unsigned short*)(chunkbase + (long)Mc * 32768L);
  unsigned short* UVTbuf = (unsigned short*)(chunkbase + (long)Mc * 36864L);

  // merged prep: 2048 cvt + 16384 W1 + 4096 W2 + 512*3 (Won1 x2, Wc1)
  prep_kernel<<<dim3(24064), 256, 0, stream>>>(input, W1, W2, Won1, Wc1,
                                               inputb, W1T, W2T, WcatT, Wc1T);

  const int nyc = Mc / 128;
  const int GM = (nyc % 4 == 0) ? 4 : ((nyc % 2 == 0) ? 2 : 1);

  for (int cc = 0; cc < nc; ++cc) {
    const long b0 = (long)cc * Mc;
    // G1: h[k] = relu(input @ W1[k] + b1[k])   [Mc,2048]
    gemm_bf16<true, true><<<dim3(16 * nyc * 8), 256, 0, stream>>>(
        inputb + b0 * 1024, W1T, b1, hbuf, 2048, 1024, 16, nyc, GM,
        0L, (long)2048 * 1024, 2048L, (long)Mc * 2048);
    // G2: emb[k] = h[k] @ W2[k] + b2[k]        [Mc,256]
    gemm_bf16<true, false><<<dim3(2 * nyc * 8), 256, 0, stream>>>(
        hbuf, W2T, b2, embbuf, 256, 2048, 2, nyc, GM,
        (long)Mc * 2048, (long)256 * 2048, 256L, (long)Mc * 256);
    // G3: UVT[k] = emb[k] @ [Won1_top | Won1_bot]   [Mc,4096], K=256 single-panel
    gemm_k256<<<dim3(32 * nyc * 8), 256, 0, stream>>>(
        embbuf, WcatT, UVTbuf, 32, nyc, GM, (long)Mc * 256, (long)Mc * 4096);
    // on[p,b]
    pair_reduce_kernel<<<dim3(Mc), 256, 0, stream>>>(
        UVTbuf, bon1, Won2, bon2, out + b0 * 64, Mc);
    // clear[k,b]
    clear_fused<<<dim3(nyc, 8), 256, 0, stream>>>(embbuf, Wc1T, bc1, Wc2, bc2, out + b0 * 64, Mc);
  }
}

// Round 5
// 674.826 us; speedup vs baseline: 1.1412x; 1.1412x over previous
//
#include <hip/hip_runtime.h>

typedef __attribute__((ext_vector_type(8))) short bf16x8;
typedef __attribute__((ext_vector_type(4))) float f32x4;
typedef __attribute__((ext_vector_type(8))) unsigned short u16x8;

__device__ __forceinline__ float bf2f(short s) {
  unsigned u = ((unsigned)(unsigned short)s) << 16;
  return __builtin_bit_cast(float, u);
}
__device__ __forceinline__ unsigned short f2bf(float f) {
  unsigned u = __builtin_bit_cast(unsigned, f);
  u = (u + 0x7fffu + ((u >> 16) & 1u)) >> 16;
  return (unsigned short)u;
}
__device__ __forceinline__ void gload16(const unsigned short* g, unsigned short* l) {
  __builtin_amdgcn_global_load_lds(
      (const __attribute__((address_space(1))) void*)g,
      (__attribute__((address_space(3))) void*)l, 16, 0, 0);
}

// ---------------- merged prep: input cvt + all 5 weight transposes ----------------
__global__ __launch_bounds__(256)
void prep_kernel(const float* __restrict__ input, const float* __restrict__ W1,
                 const float* __restrict__ W2, const float* __restrict__ Won1,
                 const float* __restrict__ Wc1,
                 unsigned short* __restrict__ inputb, unsigned short* __restrict__ W1T,
                 unsigned short* __restrict__ W2T, unsigned short* __restrict__ WcatT,
                 unsigned short* __restrict__ Wc1T) {
  int bid = blockIdx.x;
  const int t = threadIdx.x;
  if (bid < 2048) {  // cvt input -> bf16 (4096x1024)
    long i = ((long)bid * 256 + t) * 8;
    float4 a = *(const float4*)(input + i);
    float4 b = *(const float4*)(input + i + 4);
    u16x8 o;
    o[0] = f2bf(a.x); o[1] = f2bf(a.y); o[2] = f2bf(a.z); o[3] = f2bf(a.w);
    o[4] = f2bf(b.x); o[5] = f2bf(b.y); o[6] = f2bf(b.z); o[7] = f2bf(b.w);
    *(u16x8*)(inputb + i) = o;
    return;
  }
  bid -= 2048;
  const float* src; unsigned short* dst;
  int R, C, tilesX, tilesY; long sb, db;
  if (bid < 16384) {                    // W1[k][1024,2048] -> W1T[k][2048,1024]
    src = W1; dst = W1T; R = 1024; C = 2048; tilesX = 64; tilesY = 32;
    sb = 2097152; db = 2097152;
  } else if ((bid -= 16384) < 4096) {   // W2[k][2048,256] -> W2T[k][256,2048]
    src = W2; dst = W2T; R = 2048; C = 256; tilesX = 8; tilesY = 64;
    sb = 524288; db = 524288;
  } else if ((bid -= 4096) < 512) {     // Won1 top half -> WcatT[0:2048]
    src = Won1; dst = WcatT; R = 256; C = 2048; tilesX = 64; tilesY = 8;
    sb = 0; db = 0;
  } else if ((bid -= 512) < 512) {      // Won1 bottom half -> WcatT[2048:4096]
    src = Won1 + 524288; dst = WcatT + (long)2048 * 256;
    R = 256; C = 2048; tilesX = 64; tilesY = 8; sb = 0; db = 0;
  } else {                              // Wc1 -> Wc1T[2048,256]
    bid -= 512;
    src = Wc1; dst = Wc1T; R = 256; C = 2048; tilesX = 64; tilesY = 8;
    sb = 0; db = 0;
  }
  const int x = bid % tilesX;
  const int rem = bid / tilesX;
  const int y = rem % tilesY;
  const int z = rem / tilesY;
  src += (long)z * sb;
  dst += (long)z * db;
  __shared__ float tile[32][33];
  const int tx = t & 31, ty = t >> 5;
  const int bx = x * 32, by = y * 32;
  #pragma unroll
  for (int i = ty; i < 32; i += 8)
    tile[i][tx] = src[(long)(by + i) * C + bx + tx];
  __syncthreads();
  #pragma unroll
  for (int i = ty; i < 32; i += 8)
    dst[(long)(bx + i) * R + by + tx] = f2bf(tile[tx][i]);
}

// ---------------- bf16 MFMA GEMM: C[M,N] = A[M,K] @ Bt[N,K]^T ----------------
// m97 structure: 128x128 tile, BK=64, 4 waves (2x2), global_load_lds staging,
// linear LDS, 2-barrier loop. XCD-chunked bijective swizzle + GM supergroup.
template<bool HAS_BIAS, bool RELU>
__global__ __launch_bounds__(256, 3)
void gemm_bf16(const unsigned short* __restrict__ A,
               const unsigned short* __restrict__ Bt,
               const float* __restrict__ bias,
               unsigned short* __restrict__ C,
               int N, int K, int nx, int ny, int GM,
               long sA, long sB, long sBias, long sC) {
  __shared__ unsigned short As[128 * 64];
  __shared__ unsigned short Bs[128 * 64];
  const int t = threadIdx.x;
  const int lane = t & 63;
  const int w = t >> 6, wr = w >> 1, wc = w & 1;

  const int nwg = gridDim.x;
  const int cpx = nwg >> 3;
  const int id = blockIdx.x;
  const int sw = (id & 7) * cpx + (id >> 3);
  const int z = sw / (nx * ny);
  const int rem = sw % (nx * ny);
  const int band = rem / (GM * nx);
  const int r = rem % (GM * nx);
  const int y = band * GM + (r % GM);
  const int x = r / GM;
  const int m0 = y * 128, n0 = x * 128;

  A += (long)z * sA;
  Bt += (long)z * sB;
  C += (long)z * sC;

  const int po = w * 4;
  const int prow = lane >> 3;
  const int pcol = (lane & 7) * 8;

  f32x4 acc[4][4] = {};

  for (int kt = 0; kt < K; kt += 64) {
    __syncthreads();
    #pragma unroll
    for (int p = 0; p < 4; ++p) {
      const int q = po + p;
      const int row = q * 8 + prow;
      gload16(A + (long)(m0 + row) * K + kt + pcol, As + q * 512);
      gload16(Bt + (long)(n0 + row) * K + kt + pcol, Bs + q * 512);
    }
    __syncthreads();
    #pragma unroll
    for (int ks = 0; ks < 2; ++ks) {
      bf16x8 af[4], bfr[4];
      #pragma unroll
      for (int mi = 0; mi < 4; ++mi) {
        const int row = wr * 64 + mi * 16 + (lane & 15);
        af[mi] = *(const bf16x8*)((const char*)As + row * 128 + ks * 64 + (lane >> 4) * 16);
      }
      #pragma unroll
      for (int ni = 0; ni < 4; ++ni) {
        const int row = wc * 64 + ni * 16 + (lane & 15);
        bfr[ni] = *(const bf16x8*)((const char*)Bs + row * 128 + ks * 64 + (lane >> 4) * 16);
      }
      #pragma unroll
      for (int mi = 0; mi < 4; ++mi)
        #pragma unroll
        for (int ni = 0; ni < 4; ++ni)
          acc[mi][ni] = __builtin_amdgcn_mfma_f32_16x16x32_bf16(af[mi], bfr[ni], acc[mi][ni], 0, 0, 0);
    }
  }

  #pragma unroll
  for (int mi = 0; mi < 4; ++mi) {
    #pragma unroll
    for (int ni = 0; ni < 4; ++ni) {
      const int colg = n0 + wc * 64 + ni * 16 + (lane & 15);
      float bv = 0.f;
      if (HAS_BIAS) bv = bias[(long)z * sBias + colg];
      #pragma unroll
      for (int r2 = 0; r2 < 4; ++r2) {
        const int rowg = m0 + wr * 64 + mi * 16 + (lane >> 4) * 4 + r2;
        float v = acc[mi][ni][r2] + bv;
        if (RELU) v = fmaxf(v, 0.f);
        C[(long)rowg * N + colg] = f2bf(v);
      }
    }
  }
}

// ---------------- fused clear heads, 64-row blocks ----------------
// clear[k,b] = Wc2 . relu(emb[k,b,:] @ Wc1 + bc1). Block = (64 b-rows, k).
// emb tile [64,256] resident in LDS (XOR-swizzled); Wc1T streamed per K-step
// via global_load_lds; dot with Wc2 accumulated in registers.
__global__ __launch_bounds__(256, 3)
void clear_fused(const unsigned short* __restrict__ emb,   // [8][Mc][256]
                 const unsigned short* __restrict__ Wc1T,  // [2048][256]
                 const float* __restrict__ bc1, const float* __restrict__ Wc2,
                 const float* __restrict__ bc2,
                 float* __restrict__ out, int Mc) {
  __shared__ unsigned short Ae[64 * 256];   // 32KB, XOR-swizzled rows of 512B
  __shared__ unsigned short Bs[128 * 64];   // 16KB linear
  __shared__ float red[4][64];
  const int t = threadIdx.x;
  const int lane = t & 63;
  const int w = t >> 6;                     // wave owns n in [w*32, w*32+32)
  const int k = blockIdx.y;
  const int m0 = blockIdx.x * 64;
  const unsigned short* A = emb + ((long)k * Mc + m0) * 256;

  // stage emb tile once (reg path, swizzled)
  #pragma unroll
  for (int pass = 0; pass < 8; ++pass) {
    const int row = pass * 8 + (t >> 5);
    const int sc = t & 31;
    float4 v = *(const float4*)(A + (long)row * 256 + sc * 8);
    *(float4*)((char*)Ae + row * 512 + ((sc * 16) ^ ((row & 7) << 4))) = v;
  }

  float rsum[4][4] = {};  // [mi][r]

  for (int nt = 0; nt < 16; ++nt) {
    f32x4 acc[4][2] = {};
    for (int kt = 0; kt < 256; kt += 64) {
      __syncthreads();
      #pragma unroll
      for (int pass = 0; pass < 4; ++pass) {
        const int row = pass * 32 + (t >> 3);   // 0..127 B rows
        gload16(Wc1T + (long)(nt * 128 + row) * 256 + kt + (t & 7) * 8,
                Bs + row * 64 + (t & 7) * 8);
      }
      __syncthreads();
      #pragma unroll
      for (int ks = 0; ks < 2; ++ks) {
        bf16x8 af[4], bfr[2];
        #pragma unroll
        for (int mi = 0; mi < 4; ++mi) {
          const int row = mi * 16 + (lane & 15);
          const int ce = kt + ks * 32 + (lane >> 4) * 8;
          af[mi] = *(const bf16x8*)((const char*)Ae + row * 512 + ((ce * 2) ^ ((row & 7) << 4)));
        }
        #pragma unroll
        for (int ni = 0; ni < 2; ++ni) {
          const int row = w * 32 + ni * 16 + (lane & 15);
          bfr[ni] = *(const bf16x8*)((const char*)Bs + row * 128 + ks * 64 + (lane >> 4) * 16);
        }
        #pragma unroll
        for (int mi = 0; mi < 4; ++mi)
          #pragma unroll
          for (int ni = 0; ni < 2; ++ni)
            acc[mi][ni] = __builtin_amdgcn_mfma_f32_16x16x32_bf16(af[mi], bfr[ni], acc[mi][ni], 0, 0, 0);
      }
    }
    #pragma unroll
    for (int mi = 0; mi < 4; ++mi) {
      #pragma unroll
      for (int ni = 0; ni < 2; ++ni) {
        const int col = nt * 128 + w * 32 + ni * 16 + (lane & 15);
        const float bv = bc1[col], wv = Wc2[col];
        #pragma unroll
        for (int r = 0; r < 4; ++r)
          rsum[mi][r] += fmaxf(acc[mi][ni][r] + bv, 0.f) * wv;
      }
    }
  }

  // reduce over the 16 col-lanes of each group
  #pragma unroll
  for (int off = 1; off < 16; off <<= 1)
    #pragma unroll
    for (int mi = 0; mi < 4; ++mi)
      #pragma unroll
      for (int r = 0; r < 4; ++r)
        rsum[mi][r] += __shfl_xor(rsum[mi][r], off, 64);
  if ((lane & 15) == 0) {
    #pragma unroll
    for (int mi = 0; mi < 4; ++mi)
      #pragma unroll
      for (int r = 0; r < 4; ++r)
        red[w][mi * 16 + (lane >> 4) * 4 + r] = rsum[mi][r];
  }
  __syncthreads();
  if (t < 64)
    out[(long)(m0 + t) * 64 + 56 + k] =
        red[0][t] + red[1][t] + red[2][t] + red[3][t] + bc2[0];
}

// ---------------- pairwise reduce: on[p,b] ----------------
__global__ __launch_bounds__(256)
void pair_reduce_kernel(const unsigned short* __restrict__ UVT,  // [8][Mc][4096]
                        const float* __restrict__ bon1, const float* __restrict__ Won2,
                        const float* __restrict__ bon2,
                        float* __restrict__ out, int Mc) {
  __shared__ unsigned short uv[8 * 4096];
  const int b = blockIdx.x, t = threadIdx.x;
  const long kstride = (long)Mc * 4096;
  const unsigned short* src = UVT + (long)b * 4096;
  for (int k = 0; k < 8; ++k) {
    const unsigned short* s = src + (long)k * kstride;
    #pragma unroll
    for (int c0 = 0; c0 < 2; ++c0) {
      int c = c0 * 256 + t;
      int byte = k * 8192 + ((c * 16) ^ ((k & 7) << 4));
      *(float4*)((char*)uv + byte) = *(const float4*)(s + c * 8);
    }
  }
  __syncthreads();
  const int p = t & 63, q = t >> 6;
  float acc = 0.f;
  if (p < 56) {
    const int i = p / 7;
    const int jj = p % 7;
    const int j = jj + (jj >= i);
    const char* ubase = (const char*)uv + i * 8192;
    const char* vbase = (const char*)uv + j * 8192;
    const int uswz = (i & 7) << 4, vswz = (j & 7) << 4;
    for (int it = 0; it < 64; ++it) {
      const int h = q * 512 + it * 8;
      bf16x8 uu = *(const bf16x8*)(ubase + ((h * 2) ^ uswz));
      bf16x8 vv = *(const bf16x8*)(vbase + ((4096 + h * 2) ^ vswz));
      float4 ba = *(const float4*)(bon1 + h);
      float4 bb = *(const float4*)(bon1 + h + 4);
      float4 wa = *(const float4*)(Won2 + h);
      float4 wb = *(const float4*)(Won2 + h + 4);
      float bs[8] = {ba.x, ba.y, ba.z, ba.w, bb.x, bb.y, bb.z, bb.w};
      float wv[8] = {wa.x, wa.y, wa.z, wa.w, wb.x, wb.y, wb.z, wb.w};
      #pragma unroll
      for (int e = 0; e < 8; ++e) {
        float xv = bf2f(uu[e]) + bf2f(vv[e]) + bs[e];
        acc += fmaxf(xv, 0.f) * wv[e];
      }
    }
  }
  __syncthreads();
  float* red = (float*)uv;
  red[q * 64 + p] = acc;
  __syncthreads();
  if (t < 56)
    out[(long)b * 64 + t] = red[t] + red[64 + t] + red[128 + t] + red[192 + t] + bon2[0];
}

extern "C" void kernel_launch(void* const* d_in, const int* in_sizes, int n_in,
                              void* d_out, int out_size, void* d_ws, size_t ws_size,
                              hipStream_t stream) {
  (void)in_sizes; (void)n_in; (void)out_size;
  const float* input = (const float*)d_in[0];
  const float* W1    = (const float*)d_in[1];
  const float* b1    = (const float*)d_in[2];
  const float* W2    = (const float*)d_in[3];
  const float* b2    = (const float*)d_in[4];
  const float* Won1  = (const float*)d_in[5];
  const float* bon1  = (const float*)d_in[6];
  const float* Won2  = (const float*)d_in[7];
  const float* bon2  = (const float*)d_in[8];
  const float* Wc1   = (const float*)d_in[9];
  const float* bc1   = (const float*)d_in[10];
  const float* Wc2   = (const float*)d_in[11];
  const float* bc2   = (const float*)d_in[12];
  float* out = (float*)d_out;

  char* base = (char*)d_ws;
  unsigned short* inputb = (unsigned short*)(base);                  //  8 MB
  unsigned short* W1T    = (unsigned short*)(base + 8388608L);       // 32 MB [8][2048][1024]
  unsigned short* W2T    = (unsigned short*)(base + 41943040L);      //  8 MB [8][256][2048]
  unsigned short* WcatT  = (unsigned short*)(base + 50331648L);      //  2 MB [4096][256]
  unsigned short* Wc1T   = (unsigned short*)(base + 52428800L);      //  1 MB [2048][256]
  char* chunkbase = base + 53477376L;

  // per-chunk bytes = Mc * (32768 h + 4096 emb + 65536 UVT) = Mc * 102400
  int nc = 32;
  const int opts[6] = {1, 2, 4, 8, 16, 32};
  for (int oi = 0; oi < 6; ++oi) {
    long Mc_ = 4096 / opts[oi];
    if (53477376L + Mc_ * 102400L <= (long)ws_size) { nc = opts[oi]; break; }
  }
  const int Mc = 4096 / nc;
  unsigned short* hbuf   = (unsigned short*)chunkbase;
  unsigned short* embbuf = (unsigned short*)(chunkbase + (long)Mc * 32768L);
  unsigned short* UVTbuf = (unsigned short*)(chunkbase + (long)Mc * 36864L);

  // merged prep: 2048 cvt + 16384 W1 + 4096 W2 + 512*3 (Won1 x2, Wc1)
  prep_kernel<<<dim3(24064), 256, 0, stream>>>(input, W1, W2, Won1, Wc1,
                                               inputb, W1T, W2T, WcatT, Wc1T);

  const int nyc = Mc / 128;
  const int GM = (nyc % 4 == 0) ? 4 : ((nyc % 2 == 0) ? 2 : 1);

  for (int cc = 0; cc < nc; ++cc) {
    const long b0 = (long)cc * Mc;
    // G1: h[k] = relu(input @ W1[k] + b1[k])   [Mc,2048]
    gemm_bf16<true, true><<<dim3(16 * nyc * 8), 256, 0, stream>>>(
        inputb + b0 * 1024, W1T, b1, hbuf, 2048, 1024, 16, nyc, GM,
        0L, (long)2048 * 1024, 2048L, (long)Mc * 2048);
    // G2: emb[k] = h[k] @ W2[k] + b2[k]        [Mc,256]
    gemm_bf16<true, false><<<dim3(2 * nyc * 8), 256, 0, stream>>>(
        hbuf, W2T, b2, embbuf, 256, 2048, 2, nyc, GM,
        (long)Mc * 2048, (long)256 * 2048, 256L, (long)Mc * 256);
    // G3: UVT[k] = emb[k] @ [Won1_top | Won1_bot]   [Mc,4096]
    gemm_bf16<false, false><<<dim3(32 * nyc * 8), 256, 0, stream>>>(
        embbuf, WcatT, nullptr, UVTbuf, 4096, 256, 32, nyc, GM,
        (long)Mc * 256, 0L, 0L, (long)Mc * 4096);
    // on[p,b]
    pair_reduce_kernel<<<dim3(Mc), 256, 0, stream>>>(
        UVTbuf, bon1, Won2, bon2, out + b0 * 64, Mc);
    // clear[k,b], 64-row blocks
    clear_fused<<<dim3(Mc / 64, 8), 256, 0, stream>>>(
        embbuf, Wc1T, bc1, Wc2, bc2, out + b0 * 64, Mc);
  }
}

// Round 6
// 655.350 us; speedup vs baseline: 1.1752x; 1.0297x over previous
//
#include <hip/hip_runtime.h>

typedef __attribute__((ext_vector_type(8))) short bf16x8;
typedef __attribute__((ext_vector_type(4))) float f32x4;
typedef __attribute__((ext_vector_type(8))) unsigned short u16x8;

__device__ __forceinline__ float bf2f(short s) {
  unsigned u = ((unsigned)(unsigned short)s) << 16;
  return __builtin_bit_cast(float, u);
}
__device__ __forceinline__ unsigned short f2bf(float f) {
  unsigned u = __builtin_bit_cast(unsigned, f);
  u = (u + 0x7fffu + ((u >> 16) & 1u)) >> 16;
  return (unsigned short)u;
}
__device__ __forceinline__ void gload16(const unsigned short* g, unsigned short* l) {
  __builtin_amdgcn_global_load_lds(
      (const __attribute__((address_space(1))) void*)g,
      (__attribute__((address_space(3))) void*)l, 16, 0, 0);
}

// ---------------- merged prep: input cvt + all 5 weight transposes ----------------
__global__ __launch_bounds__(256)
void prep_kernel(const float* __restrict__ input, const float* __restrict__ W1,
                 const float* __restrict__ W2, const float* __restrict__ Won1,
                 const float* __restrict__ Wc1,
                 unsigned short* __restrict__ inputb, unsigned short* __restrict__ W1T,
                 unsigned short* __restrict__ W2T, unsigned short* __restrict__ WcatT,
                 unsigned short* __restrict__ Wc1T) {
  int bid = blockIdx.x;
  const int t = threadIdx.x;
  if (bid < 2048) {  // cvt input -> bf16 (4096x1024)
    long i = ((long)bid * 256 + t) * 8;
    float4 a = *(const float4*)(input + i);
    float4 b = *(const float4*)(input + i + 4);
    u16x8 o;
    o[0] = f2bf(a.x); o[1] = f2bf(a.y); o[2] = f2bf(a.z); o[3] = f2bf(a.w);
    o[4] = f2bf(b.x); o[5] = f2bf(b.y); o[6] = f2bf(b.z); o[7] = f2bf(b.w);
    *(u16x8*)(inputb + i) = o;
    return;
  }
  bid -= 2048;
  const float* src; unsigned short* dst;
  int R, C, tilesX, tilesY; long sb, db;
  if (bid < 16384) {                    // W1[k][1024,2048] -> W1T[k][2048,1024]
    src = W1; dst = W1T; R = 1024; C = 2048; tilesX = 64; tilesY = 32;
    sb = 2097152; db = 2097152;
  } else if ((bid -= 16384) < 4096) {   // W2[k][2048,256] -> W2T[k][256,2048]
    src = W2; dst = W2T; R = 2048; C = 256; tilesX = 8; tilesY = 64;
    sb = 524288; db = 524288;
  } else if ((bid -= 4096) < 512) {     // Won1 top half -> WcatT[0:2048]
    src = Won1; dst = WcatT; R = 256; C = 2048; tilesX = 64; tilesY = 8;
    sb = 0; db = 0;
  } else if ((bid -= 512) < 512) {      // Won1 bottom half -> WcatT[2048:4096]
    src = Won1 + 524288; dst = WcatT + (long)2048 * 256;
    R = 256; C = 2048; tilesX = 64; tilesY = 8; sb = 0; db = 0;
  } else {                              // Wc1 -> Wc1T[2048,256]
    bid -= 512;
    src = Wc1; dst = Wc1T; R = 256; C = 2048; tilesX = 64; tilesY = 8;
    sb = 0; db = 0;
  }
  const int x = bid % tilesX;
  const int rem = bid / tilesX;
  const int y = rem % tilesY;
  const int z = rem / tilesY;
  src += (long)z * sb;
  dst += (long)z * db;
  __shared__ float tile[32][33];
  const int tx = t & 31, ty = t >> 5;
  const int bx = x * 32, by = y * 32;
  #pragma unroll
  for (int i = ty; i < 32; i += 8)
    tile[i][tx] = src[(long)(by + i) * C + bx + tx];
  __syncthreads();
  #pragma unroll
  for (int i = ty; i < 32; i += 8)
    dst[(long)(bx + i) * R + by + tx] = f2bf(tile[tx][i]);
}

// ---------------- bf16 MFMA GEMM: C[M,N] = A[M,K] @ Bt[N,K]^T ----------------
// m97 structure: 128x128 tile, BK=64, 4 waves (2x2), global_load_lds staging,
// linear LDS, 2-barrier loop. XCD-chunked bijective swizzle + GM supergroup.
template<bool HAS_BIAS, bool RELU>
__global__ __launch_bounds__(256, 3)
void gemm_bf16(const unsigned short* __restrict__ A,
               const unsigned short* __restrict__ Bt,
               const float* __restrict__ bias,
               unsigned short* __restrict__ C,
               int N, int K, int nx, int ny, int GM,
               long sA, long sB, long sBias, long sC) {
  __shared__ unsigned short As[128 * 64];
  __shared__ unsigned short Bs[128 * 64];
  const int t = threadIdx.x;
  const int lane = t & 63;
  const int w = t >> 6, wr = w >> 1, wc = w & 1;

  const int nwg = gridDim.x;
  const int cpx = nwg >> 3;
  const int id = blockIdx.x;
  const int sw = (id & 7) * cpx + (id >> 3);
  const int z = sw / (nx * ny);
  const int rem = sw % (nx * ny);
  const int band = rem / (GM * nx);
  const int r = rem % (GM * nx);
  const int y = band * GM + (r % GM);
  const int x = r / GM;
  const int m0 = y * 128, n0 = x * 128;

  A += (long)z * sA;
  Bt += (long)z * sB;
  C += (long)z * sC;

  const int po = w * 4;
  const int prow = lane >> 3;
  const int pcol = (lane & 7) * 8;

  f32x4 acc[4][4] = {};

  for (int kt = 0; kt < K; kt += 64) {
    __syncthreads();
    #pragma unroll
    for (int p = 0; p < 4; ++p) {
      const int q = po + p;
      const int row = q * 8 + prow;
      gload16(A + (long)(m0 + row) * K + kt + pcol, As + q * 512);
      gload16(Bt + (long)(n0 + row) * K + kt + pcol, Bs + q * 512);
    }
    __syncthreads();
    #pragma unroll
    for (int ks = 0; ks < 2; ++ks) {
      bf16x8 af[4], bfr[4];
      #pragma unroll
      for (int mi = 0; mi < 4; ++mi) {
        const int row = wr * 64 + mi * 16 + (lane & 15);
        af[mi] = *(const bf16x8*)((const char*)As + row * 128 + ks * 64 + (lane >> 4) * 16);
      }
      #pragma unroll
      for (int ni = 0; ni < 4; ++ni) {
        const int row = wc * 64 + ni * 16 + (lane & 15);
        bfr[ni] = *(const bf16x8*)((const char*)Bs + row * 128 + ks * 64 + (lane >> 4) * 16);
      }
      #pragma unroll
      for (int mi = 0; mi < 4; ++mi)
        #pragma unroll
        for (int ni = 0; ni < 4; ++ni)
          acc[mi][ni] = __builtin_amdgcn_mfma_f32_16x16x32_bf16(af[mi], bfr[ni], acc[mi][ni], 0, 0, 0);
    }
  }

  #pragma unroll
  for (int mi = 0; mi < 4; ++mi) {
    #pragma unroll
    for (int ni = 0; ni < 4; ++ni) {
      const int colg = n0 + wc * 64 + ni * 16 + (lane & 15);
      float bv = 0.f;
      if (HAS_BIAS) bv = bias[(long)z * sBias + colg];
      #pragma unroll
      for (int r2 = 0; r2 < 4; ++r2) {
        const int rowg = m0 + wr * 64 + mi * 16 + (lane >> 4) * 4 + r2;
        float v = acc[mi][ni][r2] + bv;
        if (RELU) v = fmaxf(v, 0.f);
        C[(long)rowg * N + colg] = f2bf(v);
      }
    }
  }
}

// ---------------- bf16 MFMA GEMM, 64x128 tile (for skinny-M-parallelism) ----------
// 4 waves (2x2), each wave 32x64. Same 2-barrier gload_lds structure.
template<bool HAS_BIAS, bool RELU>
__global__ __launch_bounds__(256, 4)
void gemm_bm64(const unsigned short* __restrict__ A,
               const unsigned short* __restrict__ Bt,
               const float* __restrict__ bias,
               unsigned short* __restrict__ C,
               int N, int K, int nx, int ny, int GM,
               long sA, long sB, long sBias, long sC) {
  __shared__ unsigned short As[64 * 64];    //  8KB
  __shared__ unsigned short Bs[128 * 64];   // 16KB
  const int t = threadIdx.x;
  const int lane = t & 63;
  const int w = t >> 6, wr = w >> 1, wc = w & 1;

  const int nwg = gridDim.x;
  const int cpx = nwg >> 3;
  const int id = blockIdx.x;
  const int sw = (id & 7) * cpx + (id >> 3);
  const int z = sw / (nx * ny);
  const int rem = sw % (nx * ny);
  const int band = rem / (GM * nx);
  const int r = rem % (GM * nx);
  const int y = band * GM + (r % GM);
  const int x = r / GM;
  const int m0 = y * 64, n0 = x * 128;

  A += (long)z * sA;
  Bt += (long)z * sB;
  C += (long)z * sC;

  const int prow = lane >> 3;
  const int pcol = (lane & 7) * 8;

  f32x4 acc[2][4] = {};

  for (int kt = 0; kt < K; kt += 64) {
    __syncthreads();
    #pragma unroll
    for (int p = 0; p < 2; ++p) {  // A: 64 rows in 2 passes of 32
      const int rbase = p * 32 + w * 8;
      gload16(A + (long)(m0 + rbase + prow) * K + kt + pcol, As + rbase * 64);
    }
    #pragma unroll
    for (int p = 0; p < 4; ++p) {  // B: 128 rows in 4 passes of 32
      const int rbase = p * 32 + w * 8;
      gload16(Bt + (long)(n0 + rbase + prow) * K + kt + pcol, Bs + rbase * 64);
    }
    __syncthreads();
    #pragma unroll
    for (int ks = 0; ks < 2; ++ks) {
      bf16x8 af[2], bfr[4];
      #pragma unroll
      for (int mi = 0; mi < 2; ++mi) {
        const int row = wr * 32 + mi * 16 + (lane & 15);
        af[mi] = *(const bf16x8*)((const char*)As + row * 128 + ks * 64 + (lane >> 4) * 16);
      }
      #pragma unroll
      for (int ni = 0; ni < 4; ++ni) {
        const int row = wc * 64 + ni * 16 + (lane & 15);
        bfr[ni] = *(const bf16x8*)((const char*)Bs + row * 128 + ks * 64 + (lane >> 4) * 16);
      }
      #pragma unroll
      for (int mi = 0; mi < 2; ++mi)
        #pragma unroll
        for (int ni = 0; ni < 4; ++ni)
          acc[mi][ni] = __builtin_amdgcn_mfma_f32_16x16x32_bf16(af[mi], bfr[ni], acc[mi][ni], 0, 0, 0);
    }
  }

  #pragma unroll
  for (int mi = 0; mi < 2; ++mi) {
    #pragma unroll
    for (int ni = 0; ni < 4; ++ni) {
      const int colg = n0 + wc * 64 + ni * 16 + (lane & 15);
      float bv = 0.f;
      if (HAS_BIAS) bv = bias[(long)z * sBias + colg];
      #pragma unroll
      for (int r2 = 0; r2 < 4; ++r2) {
        const int rowg = m0 + wr * 32 + mi * 16 + (lane >> 4) * 4 + r2;
        float v = acc[mi][ni][r2] + bv;
        if (RELU) v = fmaxf(v, 0.f);
        C[(long)rowg * N + colg] = f2bf(v);
      }
    }
  }
}

// ---------------- fused clear heads, 64-row blocks ----------------
__global__ __launch_bounds__(256, 3)
void clear_fused(const unsigned short* __restrict__ emb,   // [8][M][256]
                 const unsigned short* __restrict__ Wc1T,  // [2048][256]
                 const float* __restrict__ bc1, const float* __restrict__ Wc2,
                 const float* __restrict__ bc2,
                 float* __restrict__ out, int M) {
  __shared__ unsigned short Ae[64 * 256];   // 32KB, XOR-swizzled rows of 512B
  __shared__ unsigned short Bs[128 * 64];   // 16KB linear
  __shared__ float red[4][64];
  const int t = threadIdx.x;
  const int lane = t & 63;
  const int w = t >> 6;
  const int k = blockIdx.y;
  const int m0 = blockIdx.x * 64;
  const unsigned short* A = emb + ((long)k * M + m0) * 256;

  #pragma unroll
  for (int pass = 0; pass < 8; ++pass) {
    const int row = pass * 8 + (t >> 5);
    const int sc = t & 31;
    float4 v = *(const float4*)(A + (long)row * 256 + sc * 8);
    *(float4*)((char*)Ae + row * 512 + ((sc * 16) ^ ((row & 7) << 4))) = v;
  }

  float rsum[4][4] = {};

  for (int nt = 0; nt < 16; ++nt) {
    f32x4 acc[4][2] = {};
    for (int kt = 0; kt < 256; kt += 64) {
      __syncthreads();
      #pragma unroll
      for (int pass = 0; pass < 4; ++pass) {
        const int row = pass * 32 + (t >> 3);
        gload16(Wc1T + (long)(nt * 128 + row) * 256 + kt + (t & 7) * 8,
                Bs + row * 64 + (t & 7) * 8);
      }
      __syncthreads();
      #pragma unroll
      for (int ks = 0; ks < 2; ++ks) {
        bf16x8 af[4], bfr[2];
        #pragma unroll
        for (int mi = 0; mi < 4; ++mi) {
          const int row = mi * 16 + (lane & 15);
          const int ce = kt + ks * 32 + (lane >> 4) * 8;
          af[mi] = *(const bf16x8*)((const char*)Ae + row * 512 + ((ce * 2) ^ ((row & 7) << 4)));
        }
        #pragma unroll
        for (int ni = 0; ni < 2; ++ni) {
          const int row = w * 32 + ni * 16 + (lane & 15);
          bfr[ni] = *(const bf16x8*)((const char*)Bs + row * 128 + ks * 64 + (lane >> 4) * 16);
        }
        #pragma unroll
        for (int mi = 0; mi < 4; ++mi)
          #pragma unroll
          for (int ni = 0; ni < 2; ++ni)
            acc[mi][ni] = __builtin_amdgcn_mfma_f32_16x16x32_bf16(af[mi], bfr[ni], acc[mi][ni], 0, 0, 0);
      }
    }
    #pragma unroll
    for (int mi = 0; mi < 4; ++mi) {
      #pragma unroll
      for (int ni = 0; ni < 2; ++ni) {
        const int col = nt * 128 + w * 32 + ni * 16 + (lane & 15);
        const float bv = bc1[col], wv = Wc2[col];
        #pragma unroll
        for (int r = 0; r < 4; ++r)
          rsum[mi][r] += fmaxf(acc[mi][ni][r] + bv, 0.f) * wv;
      }
    }
  }

  #pragma unroll
  for (int off = 1; off < 16; off <<= 1)
    #pragma unroll
    for (int mi = 0; mi < 4; ++mi)
      #pragma unroll
      for (int r = 0; r < 4; ++r)
        rsum[mi][r] += __shfl_xor(rsum[mi][r], off, 64);
  if ((lane & 15) == 0) {
    #pragma unroll
    for (int mi = 0; mi < 4; ++mi)
      #pragma unroll
      for (int r = 0; r < 4; ++r)
        red[w][mi * 16 + (lane >> 4) * 4 + r] = rsum[mi][r];
  }
  __syncthreads();
  if (t < 64)
    out[(long)(m0 + t) * 64 + 56 + k] =
        red[0][t] + red[1][t] + red[2][t] + red[3][t] + bc2[0];
}

// ---------------- pairwise reduce: on[p,b] ----------------
__global__ __launch_bounds__(256)
void pair_reduce_kernel(const unsigned short* __restrict__ UVT,  // [8][Mc][4096]
                        const float* __restrict__ bon1, const float* __restrict__ Won2,
                        const float* __restrict__ bon2,
                        float* __restrict__ out, int Mc) {
  __shared__ unsigned short uv[8 * 4096];
  const int b = blockIdx.x, t = threadIdx.x;
  const long kstride = (long)Mc * 4096;
  const unsigned short* src = UVT + (long)b * 4096;
  for (int k = 0; k < 8; ++k) {
    const unsigned short* s = src + (long)k * kstride;
    #pragma unroll
    for (int c0 = 0; c0 < 2; ++c0) {
      int c = c0 * 256 + t;
      int byte = k * 8192 + ((c * 16) ^ ((k & 7) << 4));
      *(float4*)((char*)uv + byte) = *(const float4*)(s + c * 8);
    }
  }
  __syncthreads();
  const int p = t & 63, q = t >> 6;
  float acc = 0.f;
  if (p < 56) {
    const int i = p / 7;
    const int jj = p % 7;
    const int j = jj + (jj >= i);
    const char* ubase = (const char*)uv + i * 8192;
    const char* vbase = (const char*)uv + j * 8192;
    const int uswz = (i & 7) << 4, vswz = (j & 7) << 4;
    for (int it = 0; it < 64; ++it) {
      const int h = q * 512 + it * 8;
      bf16x8 uu = *(const bf16x8*)(ubase + ((h * 2) ^ uswz));
      bf16x8 vv = *(const bf16x8*)(vbase + ((4096 + h * 2) ^ vswz));
      float4 ba = *(const float4*)(bon1 + h);
      float4 bb = *(const float4*)(bon1 + h + 4);
      float4 wa = *(const float4*)(Won2 + h);
      float4 wb = *(const float4*)(Won2 + h + 4);
      float bs[8] = {ba.x, ba.y, ba.z, ba.w, bb.x, bb.y, bb.z, bb.w};
      float wv[8] = {wa.x, wa.y, wa.z, wa.w, wb.x, wb.y, wb.z, wb.w};
      #pragma unroll
      for (int e = 0; e < 8; ++e) {
        float xv = bf2f(uu[e]) + bf2f(vv[e]) + bs[e];
        acc += fmaxf(xv, 0.f) * wv[e];
      }
    }
  }
  __syncthreads();
  float* red = (float*)uv;
  red[q * 64 + p] = acc;
  __syncthreads();
  if (t < 56)
    out[(long)b * 64 + t] = red[t] + red[64 + t] + red[128 + t] + red[192 + t] + bon2[0];
}

extern "C" void kernel_launch(void* const* d_in, const int* in_sizes, int n_in,
                              void* d_out, int out_size, void* d_ws, size_t ws_size,
                              hipStream_t stream) {
  (void)in_sizes; (void)n_in; (void)out_size;
  const float* input = (const float*)d_in[0];
  const float* W1    = (const float*)d_in[1];
  const float* b1    = (const float*)d_in[2];
  const float* W2    = (const float*)d_in[3];
  const float* b2    = (const float*)d_in[4];
  const float* Won1  = (const float*)d_in[5];
  const float* bon1  = (const float*)d_in[6];
  const float* Won2  = (const float*)d_in[7];
  const float* bon2  = (const float*)d_in[8];
  const float* Wc1   = (const float*)d_in[9];
  const float* bc1   = (const float*)d_in[10];
  const float* Wc2   = (const float*)d_in[11];
  const float* bc2   = (const float*)d_in[12];
  float* out = (float*)d_out;

  char* base = (char*)d_ws;
  unsigned short* inputb = (unsigned short*)(base);                  //   8 MB
  unsigned short* W1T    = (unsigned short*)(base + 8388608L);       //  32 MB [8][2048][1024]
  unsigned short* W2T    = (unsigned short*)(base + 41943040L);      //   8 MB [8][256][2048]
  unsigned short* WcatT  = (unsigned short*)(base + 50331648L);      //   2 MB [4096][256]
  unsigned short* Wc1T   = (unsigned short*)(base + 52428800L);      //   1 MB [2048][256]
  unsigned short* hbuf   = (unsigned short*)(base + 53477376L);      // 128 MB [8][4096][2048]
  unsigned short* embbuf = (unsigned short*)(base + 187695104L);     //  16 MB [8][4096][256]
  unsigned short* UVTbuf = (unsigned short*)(base + 204472320L);     // Mc*64KB [8][Mc][4096]

  // adaptive UVT chunk size: largest Mc with 195 MB + Mc*64KB <= ws
  int Mc = 512;
  const int mopts[3] = {4096, 2048, 1024};
  for (int oi = 0; oi < 3; ++oi) {
    if (204472320L + (long)mopts[oi] * 65536L <= (long)ws_size) { Mc = mopts[oi]; break; }
  }
  const int nc = 4096 / Mc;

  // prep: 2048 cvt + 16384 W1 + 4096 W2 + 512*3 (Won1 x2, Wc1)
  prep_kernel<<<dim3(24064), 256, 0, stream>>>(input, W1, W2, Won1, Wc1,
                                               inputb, W1T, W2T, WcatT, Wc1T);

  // G1 full-batch: h[k] = relu(input @ W1[k] + b1[k])   [8][4096][2048]
  gemm_bf16<true, true><<<dim3(16 * 32 * 8), 256, 0, stream>>>(
      inputb, W1T, b1, hbuf, 2048, 1024, 16, 32, 4,
      0L, (long)2048 * 1024, 2048L, (long)4096 * 2048);

  // G2 full-batch (64x128 tiles): emb[k] = h[k] @ W2[k] + b2[k]   [8][4096][256]
  gemm_bm64<true, false><<<dim3(2 * 64 * 8), 256, 0, stream>>>(
      hbuf, W2T, b2, embbuf, 256, 2048, 2, 64, 4,
      (long)4096 * 2048, (long)256 * 2048, 256L, (long)4096 * 256);

  // clear heads full-batch
  clear_fused<<<dim3(64, 8), 256, 0, stream>>>(embbuf, Wc1T, bc1, Wc2, bc2, out, 4096);

  // G3 + pair reduce, chunked over b
  const int nyc = Mc / 128;
  for (int cc = 0; cc < nc; ++cc) {
    const long b0 = (long)cc * Mc;
    gemm_bf16<false, false><<<dim3(32 * nyc * 8), 256, 0, stream>>>(
        embbuf + b0 * 256, WcatT, nullptr, UVTbuf, 4096, 256, 32, nyc, 4,
        (long)4096 * 256, 0L, 0L, (long)Mc * 4096);
    pair_reduce_kernel<<<dim3(Mc), 256, 0, stream>>>(
        UVTbuf, bon1, Won2, bon2, out + b0 * 64, Mc);
  }
}

// Round 7
// 631.150 us; speedup vs baseline: 1.2202x; 1.0383x over previous
//
#include <hip/hip_runtime.h>

typedef __attribute__((ext_vector_type(8))) short bf16x8;
typedef __attribute__((ext_vector_type(4))) float f32x4;
typedef __attribute__((ext_vector_type(8))) unsigned short u16x8;

__device__ __forceinline__ float bf2f(short s) {
  unsigned u = ((unsigned)(unsigned short)s) << 16;
  return __builtin_bit_cast(float, u);
}
__device__ __forceinline__ unsigned short f2bf(float f) {
  unsigned u = __builtin_bit_cast(unsigned, f);
  u = (u + 0x7fffu + ((u >> 16) & 1u)) >> 16;
  return (unsigned short)u;
}
__device__ __forceinline__ void gload16(const unsigned short* g, unsigned short* l) {
  __builtin_amdgcn_global_load_lds(
      (const __attribute__((address_space(1))) void*)g,
      (__attribute__((address_space(3))) void*)l, 16, 0, 0);
}

// ---------------- merged prep: input cvt + all 5 weight transposes ----------------
__global__ __launch_bounds__(256)
void prep_kernel(const float* __restrict__ input, const float* __restrict__ W1,
                 const float* __restrict__ W2, const float* __restrict__ Won1,
                 const float* __restrict__ Wc1,
                 unsigned short* __restrict__ inputb, unsigned short* __restrict__ W1T,
                 unsigned short* __restrict__ W2T, unsigned short* __restrict__ WcatT,
                 unsigned short* __restrict__ Wc1T) {
  int bid = blockIdx.x;
  const int t = threadIdx.x;
  if (bid < 2048) {  // cvt input -> bf16 (4096x1024)
    long i = ((long)bid * 256 + t) * 8;
    float4 a = *(const float4*)(input + i);
    float4 b = *(const float4*)(input + i + 4);
    u16x8 o;
    o[0] = f2bf(a.x); o[1] = f2bf(a.y); o[2] = f2bf(a.z); o[3] = f2bf(a.w);
    o[4] = f2bf(b.x); o[5] = f2bf(b.y); o[6] = f2bf(b.z); o[7] = f2bf(b.w);
    *(u16x8*)(inputb + i) = o;
    return;
  }
  bid -= 2048;
  const float* src; unsigned short* dst;
  int R, C, tilesX, tilesY; long sb, db;
  if (bid < 16384) {                    // W1[k][1024,2048] -> W1T[k][2048,1024]
    src = W1; dst = W1T; R = 1024; C = 2048; tilesX = 64; tilesY = 32;
    sb = 2097152; db = 2097152;
  } else if ((bid -= 16384) < 4096) {   // W2[k][2048,256] -> W2T[k][256,2048]
    src = W2; dst = W2T; R = 2048; C = 256; tilesX = 8; tilesY = 64;
    sb = 524288; db = 524288;
  } else if ((bid -= 4096) < 512) {     // Won1 top half -> WcatT[0:2048]
    src = Won1; dst = WcatT; R = 256; C = 2048; tilesX = 64; tilesY = 8;
    sb = 0; db = 0;
  } else if ((bid -= 512) < 512) {      // Won1 bottom half -> WcatT[2048:4096]
    src = Won1 + 524288; dst = WcatT + (long)2048 * 256;
    R = 256; C = 2048; tilesX = 64; tilesY = 8; sb = 0; db = 0;
  } else {                              // Wc1 -> Wc1T[2048,256]
    bid -= 512;
    src = Wc1; dst = Wc1T; R = 256; C = 2048; tilesX = 64; tilesY = 8;
    sb = 0; db = 0;
  }
  const int x = bid % tilesX;
  const int rem = bid / tilesX;
  const int y = rem % tilesY;
  const int z = rem / tilesY;
  src += (long)z * sb;
  dst += (long)z * db;
  __shared__ float tile[32][33];
  const int tx = t & 31, ty = t >> 5;
  const int bx = x * 32, by = y * 32;
  #pragma unroll
  for (int i = ty; i < 32; i += 8)
    tile[i][tx] = src[(long)(by + i) * C + bx + tx];
  __syncthreads();
  #pragma unroll
  for (int i = ty; i < 32; i += 8)
    dst[(long)(bx + i) * R + by + tx] = f2bf(tile[tx][i]);
}

// ---------------- 8-phase 256x256 GEMM (T2+T3+T4+T5): C = A[M,K] @ Bt[N,K]^T ----
// 512 threads, 8 waves (2M x 4N), BK=64, LDS 128KB = 2 dbuf x {A 2half, B 2half}
// x 16KB. Half-tile order per K-tile: [Blo,Bhi,Alo,Ahi]; stage s = 7+8i+phase.
// vmcnt(6) at phases 4/8 (3 half-tiles in flight); swizzle byte ^= (row&7)<<4
// on reads, inverse-swizzled global source for global_load_lds (linear dest).
template<bool HAS_BIAS, bool RELU>
__global__ __launch_bounds__(512, 1)
void gemm256(const unsigned short* __restrict__ A,
             const unsigned short* __restrict__ Bt,
             const float* __restrict__ bias,
             unsigned short* __restrict__ C,
             int N, int K, int nx, int ny, int GM,
             long sA, long sB, long sBias, long sC) {
  __shared__ unsigned short lds[65536];  // 128KB
  const int t = threadIdx.x;
  const int lane = t & 63;
  const int w = t >> 6, wr = w >> 2, wc = w & 3;

  const int nwg = gridDim.x;
  const int cpx = nwg >> 3;
  const int id = blockIdx.x;
  const int sw = (id & 7) * cpx + (id >> 3);
  const int z = sw / (nx * ny);
  const int rem = sw % (nx * ny);
  const int band = rem / (GM * nx);
  const int rr = rem % (GM * nx);
  const int y = band * GM + (rr % GM);
  const int x = rr / GM;
  const int m0 = y * 256, n0 = x * 256;

  A += (long)z * sA;
  Bt += (long)z * sB;
  C += (long)z * sC;

  const int NH = K >> 4;      // half-tiles total (K/64 Ktiles * 4)
  const int ITERS = K >> 7;   // 2 K-tiles per iteration

  // staging geometry (per thread: 2x16B per half-tile)
  const int sr0 = t >> 3;             // row for j=0 (j=1: +64)
  const int sc0 = (t & 7) * 16;       // dest col-byte
  // frag-read constants
  const int cks0 = (((lane >> 4) * 16)) ^ ((lane & 7) << 4);
  const int cks1 = (64 + ((lane >> 4) * 16)) ^ ((lane & 7) << 4);
  const int aoff = wr * 16384 + (lane & 15) * 128;                    // A region
  const int boff = 32768 + (wc >> 1) * 16384 + ((wc & 1) * 64 + (lane & 15)) * 128;

  f32x4 acc[8][4] = {};
  bf16x8 af[4][2];
  bf16x8 bfr[2][2][2];

#define STAGE(S) do { if ((S) < NH) {                                          \
    const int kt_ = (S) >> 2, slot_ = (S) & 3;                                 \
    const int base_ = ((kt_ & 1) << 16) + ((slot_ < 2) ? 32768 : 0)            \
                      + ((slot_ & 1) << 14);                                   \
    const unsigned short* gb_;                                                 \
    _Pragma("unroll")                                                          \
    for (int j_ = 0; j_ < 2; ++j_) {                                           \
      const int r_ = sr0 + j_ * 64;                                            \
      const int yc_ = sc0 ^ ((r_ & 7) << 4);                                   \
      if (slot_ < 2)                                                           \
        gb_ = Bt + (long)(n0 + (slot_ & 1) * 128 + r_) * K + kt_ * 64 + (yc_ >> 1); \
      else                                                                     \
        gb_ = A + (long)(m0 + (slot_ & 1) * 128 + r_) * K + kt_ * 64 + (yc_ >> 1);  \
      gload16(gb_, lds + (base_ >> 1) + j_ * 4096 + t * 8);                    \
    } } } while (0)

#define LDA_(BUF, HM) do { _Pragma("unroll")                                   \
    for (int mi_ = 0; mi_ < 4; ++mi_) {                                        \
      af[mi_][0] = *(const bf16x8*)((const char*)lds + (BUF) * 65536 + aoff + ((HM) * 4 + mi_) * 2048 + cks0); \
      af[mi_][1] = *(const bf16x8*)((const char*)lds + (BUF) * 65536 + aoff + ((HM) * 4 + mi_) * 2048 + cks1); \
    } } while (0)

#define LDB_(BUF, HN) do { _Pragma("unroll")                                   \
    for (int ni_ = 0; ni_ < 2; ++ni_) {                                        \
      bfr[HN][ni_][0] = *(const bf16x8*)((const char*)lds + (BUF) * 65536 + boff + ((HN) * 2 + ni_) * 2048 + cks0); \
      bfr[HN][ni_][1] = *(const bf16x8*)((const char*)lds + (BUF) * 65536 + boff + ((HN) * 2 + ni_) * 2048 + cks1); \
    } } while (0)

#define DO_MFMA(HM, HN) do { _Pragma("unroll")                                 \
    for (int mi_ = 0; mi_ < 4; ++mi_) { _Pragma("unroll")                      \
      for (int ni_ = 0; ni_ < 2; ++ni_) { _Pragma("unroll")                    \
        for (int ks_ = 0; ks_ < 2; ++ks_)                                      \
          acc[(HM) * 4 + mi_][(HN) * 2 + ni_] =                                \
            __builtin_amdgcn_mfma_f32_16x16x32_bf16(af[mi_][ks_], bfr[HN][ni_][ks_], \
                acc[(HM) * 4 + mi_][(HN) * 2 + ni_], 0, 0, 0);                 \
    } } } while (0)

#define PHASE(MB) do {                                                         \
    __builtin_amdgcn_s_barrier();                                              \
    asm volatile("s_waitcnt lgkmcnt(0)" ::: "memory");                         \
    __builtin_amdgcn_sched_barrier(0);                                         \
    __builtin_amdgcn_s_setprio(1);                                             \
    MB;                                                                        \
    __builtin_amdgcn_s_setprio(0);                                             \
    __builtin_amdgcn_s_barrier();                                              \
  } while (0)

  // prologue: K0 (4 halves) + K1 {Blo,Bhi,Alo}
  STAGE(0); STAGE(1); STAGE(2); STAGE(3);
  asm volatile("s_waitcnt vmcnt(4)" ::: "memory");
  STAGE(4); STAGE(5); STAGE(6);
  asm volatile("s_waitcnt vmcnt(6)" ::: "memory");
  __builtin_amdgcn_s_barrier();

  for (int i = 0; i < ITERS; ++i) {
    const int s0 = 7 + (i << 3);
    const bool last = (i == ITERS - 1);
    // ---- K-tile 2i (buf 0) ----
    LDA_(0, 0); LDB_(0, 0); STAGE(s0 + 0);
    PHASE(DO_MFMA(0, 0));
    LDB_(0, 1);             STAGE(s0 + 1);
    PHASE(DO_MFMA(0, 1));
    LDA_(0, 1);             STAGE(s0 + 2);
    PHASE(DO_MFMA(1, 1));
                            STAGE(s0 + 3);
    if (last) asm volatile("s_waitcnt vmcnt(0)" ::: "memory");
    else      asm volatile("s_waitcnt vmcnt(6)" ::: "memory");
    PHASE(DO_MFMA(1, 0));
    // ---- K-tile 2i+1 (buf 1) ----
    LDA_(1, 0); LDB_(1, 0); STAGE(s0 + 4);
    PHASE(DO_MFMA(0, 0));
    LDB_(1, 1);             STAGE(s0 + 5);
    PHASE(DO_MFMA(0, 1));
    LDA_(1, 1);             STAGE(s0 + 6);
    PHASE(DO_MFMA(1, 1));
                            STAGE(s0 + 7);
    if (!last) asm volatile("s_waitcnt vmcnt(6)" ::: "memory");
    PHASE(DO_MFMA(1, 0));
  }

#undef STAGE
#undef LDA_
#undef LDB_
#undef DO_MFMA
#undef PHASE

  #pragma unroll
  for (int Mi = 0; Mi < 8; ++Mi) {
    #pragma unroll
    for (int Ni = 0; Ni < 4; ++Ni) {
      const int colg = n0 + wc * 64 + Ni * 16 + (lane & 15);
      float bv = 0.f;
      if (HAS_BIAS) bv = bias[(long)z * sBias + colg];
      #pragma unroll
      for (int r2 = 0; r2 < 4; ++r2) {
        const int rowg = m0 + wr * 128 + Mi * 16 + (lane >> 4) * 4 + r2;
        float v = acc[Mi][Ni][r2] + bv;
        if (RELU) v = fmaxf(v, 0.f);
        C[(long)rowg * N + colg] = f2bf(v);
      }
    }
  }
}

// ---------------- bf16 MFMA GEMM: 128x128, 2-phase (kept for G3) ----------------
template<bool HAS_BIAS, bool RELU>
__global__ __launch_bounds__(256, 3)
void gemm_bf16(const unsigned short* __restrict__ A,
               const unsigned short* __restrict__ Bt,
               const float* __restrict__ bias,
               unsigned short* __restrict__ C,
               int N, int K, int nx, int ny, int GM,
               long sA, long sB, long sBias, long sC) {
  __shared__ unsigned short As[128 * 64];
  __shared__ unsigned short Bs[128 * 64];
  const int t = threadIdx.x;
  const int lane = t & 63;
  const int w = t >> 6, wr = w >> 1, wc = w & 1;

  const int nwg = gridDim.x;
  const int cpx = nwg >> 3;
  const int id = blockIdx.x;
  const int sw = (id & 7) * cpx + (id >> 3);
  const int z = sw / (nx * ny);
  const int rem = sw % (nx * ny);
  const int band = rem / (GM * nx);
  const int r = rem % (GM * nx);
  const int y = band * GM + (r % GM);
  const int x = r / GM;
  const int m0 = y * 128, n0 = x * 128;

  A += (long)z * sA;
  Bt += (long)z * sB;
  C += (long)z * sC;

  const int po = w * 4;
  const int prow = lane >> 3;
  const int pcol = (lane & 7) * 8;

  f32x4 acc[4][4] = {};

  for (int kt = 0; kt < K; kt += 64) {
    __syncthreads();
    #pragma unroll
    for (int p = 0; p < 4; ++p) {
      const int q = po + p;
      const int row = q * 8 + prow;
      gload16(A + (long)(m0 + row) * K + kt + pcol, As + q * 512);
      gload16(Bt + (long)(n0 + row) * K + kt + pcol, Bs + q * 512);
    }
    __syncthreads();
    #pragma unroll
    for (int ks = 0; ks < 2; ++ks) {
      bf16x8 af[4], bfr[4];
      #pragma unroll
      for (int mi = 0; mi < 4; ++mi) {
        const int row = wr * 64 + mi * 16 + (lane & 15);
        af[mi] = *(const bf16x8*)((const char*)As + row * 128 + ks * 64 + (lane >> 4) * 16);
      }
      #pragma unroll
      for (int ni = 0; ni < 4; ++ni) {
        const int row = wc * 64 + ni * 16 + (lane & 15);
        bfr[ni] = *(const bf16x8*)((const char*)Bs + row * 128 + ks * 64 + (lane >> 4) * 16);
      }
      #pragma unroll
      for (int mi = 0; mi < 4; ++mi)
        #pragma unroll
        for (int ni = 0; ni < 4; ++ni)
          acc[mi][ni] = __builtin_amdgcn_mfma_f32_16x16x32_bf16(af[mi], bfr[ni], acc[mi][ni], 0, 0, 0);
    }
  }

  #pragma unroll
  for (int mi = 0; mi < 4; ++mi) {
    #pragma unroll
    for (int ni = 0; ni < 4; ++ni) {
      const int colg = n0 + wc * 64 + ni * 16 + (lane & 15);
      float bv = 0.f;
      if (HAS_BIAS) bv = bias[(long)z * sBias + colg];
      #pragma unroll
      for (int r2 = 0; r2 < 4; ++r2) {
        const int rowg = m0 + wr * 64 + mi * 16 + (lane >> 4) * 4 + r2;
        float v = acc[mi][ni][r2] + bv;
        if (RELU) v = fmaxf(v, 0.f);
        C[(long)rowg * N + colg] = f2bf(v);
      }
    }
  }
}

// ---------------- bf16 MFMA GEMM, 64x128 tile (G2) ----------
template<bool HAS_BIAS, bool RELU>
__global__ __launch_bounds__(256, 4)
void gemm_bm64(const unsigned short* __restrict__ A,
               const unsigned short* __restrict__ Bt,
               const float* __restrict__ bias,
               unsigned short* __restrict__ C,
               int N, int K, int nx, int ny, int GM,
               long sA, long sB, long sBias, long sC) {
  __shared__ unsigned short As[64 * 64];
  __shared__ unsigned short Bs[128 * 64];
  const int t = threadIdx.x;
  const int lane = t & 63;
  const int w = t >> 6, wr = w >> 1, wc = w & 1;

  const int nwg = gridDim.x;
  const int cpx = nwg >> 3;
  const int id = blockIdx.x;
  const int sw = (id & 7) * cpx + (id >> 3);
  const int z = sw / (nx * ny);
  const int rem = sw % (nx * ny);
  const int band = rem / (GM * nx);
  const int r = rem % (GM * nx);
  const int y = band * GM + (r % GM);
  const int x = r / GM;
  const int m0 = y * 64, n0 = x * 128;

  A += (long)z * sA;
  Bt += (long)z * sB;
  C += (long)z * sC;

  const int prow = lane >> 3;
  const int pcol = (lane & 7) * 8;

  f32x4 acc[2][4] = {};

  for (int kt = 0; kt < K; kt += 64) {
    __syncthreads();
    #pragma unroll
    for (int p = 0; p < 2; ++p) {
      const int rbase = p * 32 + w * 8;
      gload16(A + (long)(m0 + rbase + prow) * K + kt + pcol, As + rbase * 64);
    }
    #pragma unroll
    for (int p = 0; p < 4; ++p) {
      const int rbase = p * 32 + w * 8;
      gload16(Bt + (long)(n0 + rbase + prow) * K + kt + pcol, Bs + rbase * 64);
    }
    __syncthreads();
    #pragma unroll
    for (int ks = 0; ks < 2; ++ks) {
      bf16x8 af[2], bfr[4];
      #pragma unroll
      for (int mi = 0; mi < 2; ++mi) {
        const int row = wr * 32 + mi * 16 + (lane & 15);
        af[mi] = *(const bf16x8*)((const char*)As + row * 128 + ks * 64 + (lane >> 4) * 16);
      }
      #pragma unroll
      for (int ni = 0; ni < 4; ++ni) {
        const int row = wc * 64 + ni * 16 + (lane & 15);
        bfr[ni] = *(const bf16x8*)((const char*)Bs + row * 128 + ks * 64 + (lane >> 4) * 16);
      }
      #pragma unroll
      for (int mi = 0; mi < 2; ++mi)
        #pragma unroll
        for (int ni = 0; ni < 4; ++ni)
          acc[mi][ni] = __builtin_amdgcn_mfma_f32_16x16x32_bf16(af[mi], bfr[ni], acc[mi][ni], 0, 0, 0);
    }
  }

  #pragma unroll
  for (int mi = 0; mi < 2; ++mi) {
    #pragma unroll
    for (int ni = 0; ni < 4; ++ni) {
      const int colg = n0 + wc * 64 + ni * 16 + (lane & 15);
      float bv = 0.f;
      if (HAS_BIAS) bv = bias[(long)z * sBias + colg];
      #pragma unroll
      for (int r2 = 0; r2 < 4; ++r2) {
        const int rowg = m0 + wr * 32 + mi * 16 + (lane >> 4) * 4 + r2;
        float v = acc[mi][ni][r2] + bv;
        if (RELU) v = fmaxf(v, 0.f);
        C[(long)rowg * N + colg] = f2bf(v);
      }
    }
  }
}

// ---------------- fused clear heads, 64-row blocks ----------------
__global__ __launch_bounds__(256, 3)
void clear_fused(const unsigned short* __restrict__ emb,   // [8][M][256]
                 const unsigned short* __restrict__ Wc1T,  // [2048][256]
                 const float* __restrict__ bc1, const float* __restrict__ Wc2,
                 const float* __restrict__ bc2,
                 float* __restrict__ out, int M) {
  __shared__ unsigned short Ae[64 * 256];
  __shared__ unsigned short Bs[128 * 64];
  __shared__ float red[4][64];
  const int t = threadIdx.x;
  const int lane = t & 63;
  const int w = t >> 6;
  const int k = blockIdx.y;
  const int m0 = blockIdx.x * 64;
  const unsigned short* A = emb + ((long)k * M + m0) * 256;

  #pragma unroll
  for (int pass = 0; pass < 8; ++pass) {
    const int row = pass * 8 + (t >> 5);
    const int sc = t & 31;
    float4 v = *(const float4*)(A + (long)row * 256 + sc * 8);
    *(float4*)((char*)Ae + row * 512 + ((sc * 16) ^ ((row & 7) << 4))) = v;
  }

  float rsum[4][4] = {};

  for (int nt = 0; nt < 16; ++nt) {
    f32x4 acc[4][2] = {};
    for (int kt = 0; kt < 256; kt += 64) {
      __syncthreads();
      #pragma unroll
      for (int pass = 0; pass < 4; ++pass) {
        const int row = pass * 32 + (t >> 3);
        gload16(Wc1T + (long)(nt * 128 + row) * 256 + kt + (t & 7) * 8,
                Bs + row * 64 + (t & 7) * 8);
      }
      __syncthreads();
      #pragma unroll
      for (int ks = 0; ks < 2; ++ks) {
        bf16x8 af[4], bfr[2];
        #pragma unroll
        for (int mi = 0; mi < 4; ++mi) {
          const int row = mi * 16 + (lane & 15);
          const int ce = kt + ks * 32 + (lane >> 4) * 8;
          af[mi] = *(const bf16x8*)((const char*)Ae + row * 512 + ((ce * 2) ^ ((row & 7) << 4)));
        }
        #pragma unroll
        for (int ni = 0; ni < 2; ++ni) {
          const int row = w * 32 + ni * 16 + (lane & 15);
          bfr[ni] = *(const bf16x8*)((const char*)Bs + row * 128 + ks * 64 + (lane >> 4) * 16);
        }
        #pragma unroll
        for (int mi = 0; mi < 4; ++mi)
          #pragma unroll
          for (int ni = 0; ni < 2; ++ni)
            acc[mi][ni] = __builtin_amdgcn_mfma_f32_16x16x32_bf16(af[mi], bfr[ni], acc[mi][ni], 0, 0, 0);
      }
    }
    #pragma unroll
    for (int mi = 0; mi < 4; ++mi) {
      #pragma unroll
      for (int ni = 0; ni < 2; ++ni) {
        const int col = nt * 128 + w * 32 + ni * 16 + (lane & 15);
        const float bv = bc1[col], wv = Wc2[col];
        #pragma unroll
        for (int r = 0; r < 4; ++r)
          rsum[mi][r] += fmaxf(acc[mi][ni][r] + bv, 0.f) * wv;
      }
    }
  }

  #pragma unroll
  for (int off = 1; off < 16; off <<= 1)
    #pragma unroll
    for (int mi = 0; mi < 4; ++mi)
      #pragma unroll
      for (int r = 0; r < 4; ++r)
        rsum[mi][r] += __shfl_xor(rsum[mi][r], off, 64);
  if ((lane & 15) == 0) {
    #pragma unroll
    for (int mi = 0; mi < 4; ++mi)
      #pragma unroll
      for (int r = 0; r < 4; ++r)
        red[w][mi * 16 + (lane >> 4) * 4 + r] = rsum[mi][r];
  }
  __syncthreads();
  if (t < 64)
    out[(long)(m0 + t) * 64 + 56 + k] =
        red[0][t] + red[1][t] + red[2][t] + red[3][t] + bc2[0];
}

// ---------------- pairwise reduce: on[p,b] ----------------
__global__ __launch_bounds__(256)
void pair_reduce_kernel(const unsigned short* __restrict__ UVT,  // [8][Mc][4096]
                        const float* __restrict__ bon1, const float* __restrict__ Won2,
                        const float* __restrict__ bon2,
                        float* __restrict__ out, int Mc) {
  __shared__ unsigned short uv[8 * 4096];
  const int b = blockIdx.x, t = threadIdx.x;
  const long kstride = (long)Mc * 4096;
  const unsigned short* src = UVT + (long)b * 4096;
  for (int k = 0; k < 8; ++k) {
    const unsigned short* s = src + (long)k * kstride;
    #pragma unroll
    for (int c0 = 0; c0 < 2; ++c0) {
      int c = c0 * 256 + t;
      int byte = k * 8192 + ((c * 16) ^ ((k & 7) << 4));
      *(float4*)((char*)uv + byte) = *(const float4*)(s + c * 8);
    }
  }
  __syncthreads();
  const int p = t & 63, q = t >> 6;
  float acc = 0.f;
  if (p < 56) {
    const int i = p / 7;
    const int jj = p % 7;
    const int j = jj + (jj >= i);
    const char* ubase = (const char*)uv + i * 8192;
    const char* vbase = (const char*)uv + j * 8192;
    const int uswz = (i & 7) << 4, vswz = (j & 7) << 4;
    for (int it = 0; it < 64; ++it) {
      const int h = q * 512 + it * 8;
      bf16x8 uu = *(const bf16x8*)(ubase + ((h * 2) ^ uswz));
      bf16x8 vv = *(const bf16x8*)(vbase + ((4096 + h * 2) ^ vswz));
      float4 ba = *(const float4*)(bon1 + h);
      float4 bb = *(const float4*)(bon1 + h + 4);
      float4 wa = *(const float4*)(Won2 + h);
      float4 wb = *(const float4*)(Won2 + h + 4);
      float bs[8] = {ba.x, ba.y, ba.z, ba.w, bb.x, bb.y, bb.z, bb.w};
      float wv[8] = {wa.x, wa.y, wa.z, wa.w, wb.x, wb.y, wb.z, wb.w};
      #pragma unroll
      for (int e = 0; e < 8; ++e) {
        float xv = bf2f(uu[e]) + bf2f(vv[e]) + bs[e];
        acc += fmaxf(xv, 0.f) * wv[e];
      }
    }
  }
  __syncthreads();
  float* red = (float*)uv;
  red[q * 64 + p] = acc;
  __syncthreads();
  if (t < 56)
    out[(long)b * 64 + t] = red[t] + red[64 + t] + red[128 + t] + red[192 + t] + bon2[0];
}

extern "C" void kernel_launch(void* const* d_in, const int* in_sizes, int n_in,
                              void* d_out, int out_size, void* d_ws, size_t ws_size,
                              hipStream_t stream) {
  (void)in_sizes; (void)n_in; (void)out_size;
  const float* input = (const float*)d_in[0];
  const float* W1    = (const float*)d_in[1];
  const float* b1    = (const float*)d_in[2];
  const float* W2    = (const float*)d_in[3];
  const float* b2    = (const float*)d_in[4];
  const float* Won1  = (const float*)d_in[5];
  const float* bon1  = (const float*)d_in[6];
  const float* Won2  = (const float*)d_in[7];
  const float* bon2  = (const float*)d_in[8];
  const float* Wc1   = (const float*)d_in[9];
  const float* bc1   = (const float*)d_in[10];
  const float* Wc2   = (const float*)d_in[11];
  const float* bc2   = (const float*)d_in[12];
  float* out = (float*)d_out;

  char* base = (char*)d_ws;
  unsigned short* inputb = (unsigned short*)(base);                  //   8 MB
  unsigned short* W1T    = (unsigned short*)(base + 8388608L);       //  32 MB [8][2048][1024]
  unsigned short* W2T    = (unsigned short*)(base + 41943040L);      //   8 MB [8][256][2048]
  unsigned short* WcatT  = (unsigned short*)(base + 50331648L);      //   2 MB [4096][256]
  unsigned short* Wc1T   = (unsigned short*)(base + 52428800L);      //   1 MB [2048][256]
  unsigned short* hbuf   = (unsigned short*)(base + 53477376L);      // 128 MB [8][4096][2048]
  unsigned short* embbuf = (unsigned short*)(base + 187695104L);     //  16 MB [8][4096][256]
  unsigned short* UVTbuf = (unsigned short*)(base + 204472320L);     // Mc*64KB [8][Mc][4096]

  int Mc = 512;
  const int mopts[3] = {4096, 2048, 1024};
  for (int oi = 0; oi < 3; ++oi) {
    if (204472320L + (long)mopts[oi] * 65536L <= (long)ws_size) { Mc = mopts[oi]; break; }
  }
  const int nc = 4096 / Mc;

  prep_kernel<<<dim3(24064), 256, 0, stream>>>(input, W1, W2, Won1, Wc1,
                                               inputb, W1T, W2T, WcatT, Wc1T);

  // G1 full-batch, 8-phase 256^2: h[k] = relu(input @ W1[k] + b1[k])
  gemm256<true, true><<<dim3(8 * 16 * 8), 512, 0, stream>>>(
      inputb, W1T, b1, hbuf, 2048, 1024, 8, 16, 4,
      0L, (long)2048 * 1024, 2048L, (long)4096 * 2048);

  // G2 full-batch (64x128 tiles): emb[k] = h[k] @ W2[k] + b2[k]
  gemm_bm64<true, false><<<dim3(2 * 64 * 8), 256, 0, stream>>>(
      hbuf, W2T, b2, embbuf, 256, 2048, 2, 64, 4,
      (long)4096 * 2048, (long)256 * 2048, 256L, (long)4096 * 256);

  // clear heads full-batch
  clear_fused<<<dim3(64, 8), 256, 0, stream>>>(embbuf, Wc1T, bc1, Wc2, bc2, out, 4096);

  // G3 + pair reduce, chunked over b
  const int nyc = Mc / 128;
  for (int cc = 0; cc < nc; ++cc) {
    const long b0 = (long)cc * Mc;
    gemm_bf16<false, false><<<dim3(32 * nyc * 8), 256, 0, stream>>>(
        embbuf + b0 * 256, WcatT, nullptr, UVTbuf, 4096, 256, 32, nyc, 4,
        (long)4096 * 256, 0L, 0L, (long)Mc * 4096);
    pair_reduce_kernel<<<dim3(Mc), 256, 0, stream>>>(
        UVTbuf, bon1, Won2, bon2, out + b0 * 64, Mc);
  }
}

// Round 8
// 601.482 us; speedup vs baseline: 1.2804x; 1.0493x over previous
//
#include <hip/hip_runtime.h>

typedef __attribute__((ext_vector_type(8))) short bf16x8;
typedef __attribute__((ext_vector_type(4))) float f32x4;
typedef __attribute__((ext_vector_type(8))) unsigned short u16x8;

__device__ __forceinline__ float bf2f(short s) {
  unsigned u = ((unsigned)(unsigned short)s) << 16;
  return __builtin_bit_cast(float, u);
}
__device__ __forceinline__ unsigned short f2bf(float f) {
  unsigned u = __builtin_bit_cast(unsigned, f);
  u = (u + 0x7fffu + ((u >> 16) & 1u)) >> 16;
  return (unsigned short)u;
}
__device__ __forceinline__ void gload16(const unsigned short* g, unsigned short* l) {
  __builtin_amdgcn_global_load_lds(
      (const __attribute__((address_space(1))) void*)g,
      (__attribute__((address_space(3))) void*)l, 16, 0, 0);
}

// ---------------- merged prep: input cvt + all 5 weight transposes ----------------
__global__ __launch_bounds__(256)
void prep_kernel(const float* __restrict__ input, const float* __restrict__ W1,
                 const float* __restrict__ W2, const float* __restrict__ Won1,
                 const float* __restrict__ Wc1,
                 unsigned short* __restrict__ inputb, unsigned short* __restrict__ W1T,
                 unsigned short* __restrict__ W2T, unsigned short* __restrict__ WcatT,
                 unsigned short* __restrict__ Wc1T) {
  int bid = blockIdx.x;
  const int t = threadIdx.x;
  if (bid < 2048) {  // cvt input -> bf16 (4096x1024)
    long i = ((long)bid * 256 + t) * 8;
    float4 a = *(const float4*)(input + i);
    float4 b = *(const float4*)(input + i + 4);
    u16x8 o;
    o[0] = f2bf(a.x); o[1] = f2bf(a.y); o[2] = f2bf(a.z); o[3] = f2bf(a.w);
    o[4] = f2bf(b.x); o[5] = f2bf(b.y); o[6] = f2bf(b.z); o[7] = f2bf(b.w);
    *(u16x8*)(inputb + i) = o;
    return;
  }
  bid -= 2048;
  const float* src; unsigned short* dst;
  int R, C, tilesX, tilesY; long sb, db;
  if (bid < 16384) {                    // W1[k][1024,2048] -> W1T[k][2048,1024]
    src = W1; dst = W1T; R = 1024; C = 2048; tilesX = 64; tilesY = 32;
    sb = 2097152; db = 2097152;
  } else if ((bid -= 16384) < 4096) {   // W2[k][2048,256] -> W2T[k][256,2048]
    src = W2; dst = W2T; R = 2048; C = 256; tilesX = 8; tilesY = 64;
    sb = 524288; db = 524288;
  } else if ((bid -= 4096) < 512) {     // Won1 top half -> WcatT[0:2048]
    src = Won1; dst = WcatT; R = 256; C = 2048; tilesX = 64; tilesY = 8;
    sb = 0; db = 0;
  } else if ((bid -= 512) < 512) {      // Won1 bottom half -> WcatT[2048:4096]
    src = Won1 + 524288; dst = WcatT + (long)2048 * 256;
    R = 256; C = 2048; tilesX = 64; tilesY = 8; sb = 0; db = 0;
  } else {                              // Wc1 -> Wc1T[2048,256]
    bid -= 512;
    src = Wc1; dst = Wc1T; R = 256; C = 2048; tilesX = 64; tilesY = 8;
    sb = 0; db = 0;
  }
  const int x = bid % tilesX;
  const int rem = bid / tilesX;
  const int y = rem % tilesY;
  const int z = rem / tilesY;
  src += (long)z * sb;
  dst += (long)z * db;
  __shared__ float tile[32][33];
  const int tx = t & 31, ty = t >> 5;
  const int bx = x * 32, by = y * 32;
  #pragma unroll
  for (int i = ty; i < 32; i += 8)
    tile[i][tx] = src[(long)(by + i) * C + bx + tx];
  __syncthreads();
  #pragma unroll
  for (int i = ty; i < 32; i += 8)
    dst[(long)(bx + i) * R + by + tx] = f2bf(tile[tx][i]);
}

// ---------------- 8-phase 256x256 GEMM (T2+T3+T4+T5): C = A[M,K] @ Bt[N,K]^T ----
// 512 threads, 8 waves (2M x 4N), BK=64, LDS 128KB = 2 dbuf x {A 2half, B 2half}
// x 16KB. Half-tile order per K-tile: [Blo,Bhi,Alo,Ahi]; stage s = 7+8i+phase.
// vmcnt(6) at phases 4/8 (3 half-tiles in flight); swizzle byte ^= (row&7)<<4
// on reads, inverse-swizzled global source for global_load_lds (linear dest).
// Works for any K multiple of 128 (incl. K=256: NH=16, ITERS=2).
template<bool HAS_BIAS, bool RELU>
__global__ __launch_bounds__(512, 1)
void gemm256(const unsigned short* __restrict__ A,
             const unsigned short* __restrict__ Bt,
             const float* __restrict__ bias,
             unsigned short* __restrict__ C,
             int N, int K, int nx, int ny, int GM,
             long sA, long sB, long sBias, long sC) {
  __shared__ unsigned short lds[65536];  // 128KB
  const int t = threadIdx.x;
  const int lane = t & 63;
  const int w = t >> 6, wr = w >> 2, wc = w & 3;

  const int nwg = gridDim.x;
  const int cpx = nwg >> 3;
  const int id = blockIdx.x;
  const int sw = (id & 7) * cpx + (id >> 3);
  const int z = sw / (nx * ny);
  const int rem = sw % (nx * ny);
  const int band = rem / (GM * nx);
  const int rr = rem % (GM * nx);
  const int y = band * GM + (rr % GM);
  const int x = rr / GM;
  const int m0 = y * 256, n0 = x * 256;

  A += (long)z * sA;
  Bt += (long)z * sB;
  C += (long)z * sC;

  const int NH = K >> 4;      // half-tiles total (K/64 Ktiles * 4)
  const int ITERS = K >> 7;   // 2 K-tiles per iteration

  // staging geometry (per thread: 2x16B per half-tile)
  const int sr0 = t >> 3;             // row for j=0 (j=1: +64)
  const int sc0 = (t & 7) * 16;       // dest col-byte
  // frag-read constants
  const int cks0 = (((lane >> 4) * 16)) ^ ((lane & 7) << 4);
  const int cks1 = (64 + ((lane >> 4) * 16)) ^ ((lane & 7) << 4);
  const int aoff = wr * 16384 + (lane & 15) * 128;                    // A region
  const int boff = 32768 + (wc >> 1) * 16384 + ((wc & 1) * 64 + (lane & 15)) * 128;

  f32x4 acc[8][4] = {};
  bf16x8 af[4][2];
  bf16x8 bfr[2][2][2];

#define STAGE(S) do { if ((S) < NH) {                                          \
    const int kt_ = (S) >> 2, slot_ = (S) & 3;                                 \
    const int base_ = ((kt_ & 1) << 16) + ((slot_ < 2) ? 32768 : 0)            \
                      + ((slot_ & 1) << 14);                                   \
    const unsigned short* gb_;                                                 \
    _Pragma("unroll")                                                          \
    for (int j_ = 0; j_ < 2; ++j_) {                                           \
      const int r_ = sr0 + j_ * 64;                                            \
      const int yc_ = sc0 ^ ((r_ & 7) << 4);                                   \
      if (slot_ < 2)                                                           \
        gb_ = Bt + (long)(n0 + (slot_ & 1) * 128 + r_) * K + kt_ * 64 + (yc_ >> 1); \
      else                                                                     \
        gb_ = A + (long)(m0 + (slot_ & 1) * 128 + r_) * K + kt_ * 64 + (yc_ >> 1);  \
      gload16(gb_, lds + (base_ >> 1) + j_ * 4096 + t * 8);                    \
    } } } while (0)

#define LDA_(BUF, HM) do { _Pragma("unroll")                                   \
    for (int mi_ = 0; mi_ < 4; ++mi_) {                                        \
      af[mi_][0] = *(const bf16x8*)((const char*)lds + (BUF) * 65536 + aoff + ((HM) * 4 + mi_) * 2048 + cks0); \
      af[mi_][1] = *(const bf16x8*)((const char*)lds + (BUF) * 65536 + aoff + ((HM) * 4 + mi_) * 2048 + cks1); \
    } } while (0)

#define LDB_(BUF, HN) do { _Pragma("unroll")                                   \
    for (int ni_ = 0; ni_ < 2; ++ni_) {                                        \
      bfr[HN][ni_][0] = *(const bf16x8*)((const char*)lds + (BUF) * 65536 + boff + ((HN) * 2 + ni_) * 2048 + cks0); \
      bfr[HN][ni_][1] = *(const bf16x8*)((const char*)lds + (BUF) * 65536 + boff + ((HN) * 2 + ni_) * 2048 + cks1); \
    } } while (0)

#define DO_MFMA(HM, HN) do { _Pragma("unroll")                                 \
    for (int mi_ = 0; mi_ < 4; ++mi_) { _Pragma("unroll")                      \
      for (int ni_ = 0; ni_ < 2; ++ni_) { _Pragma("unroll")                    \
        for (int ks_ = 0; ks_ < 2; ++ks_)                                      \
          acc[(HM) * 4 + mi_][(HN) * 2 + ni_] =                                \
            __builtin_amdgcn_mfma_f32_16x16x32_bf16(af[mi_][ks_], bfr[HN][ni_][ks_], \
                acc[(HM) * 4 + mi_][(HN) * 2 + ni_], 0, 0, 0);                 \
    } } } while (0)

#define PHASE(MB) do {                                                         \
    __builtin_amdgcn_s_barrier();                                              \
    asm volatile("s_waitcnt lgkmcnt(0)" ::: "memory");                         \
    __builtin_amdgcn_sched_barrier(0);                                         \
    __builtin_amdgcn_s_setprio(1);                                             \
    MB;                                                                        \
    __builtin_amdgcn_s_setprio(0);                                             \
    __builtin_amdgcn_s_barrier();                                              \
  } while (0)

  // prologue: K0 (4 halves) + K1 {Blo,Bhi,Alo}
  STAGE(0); STAGE(1); STAGE(2); STAGE(3);
  asm volatile("s_waitcnt vmcnt(4)" ::: "memory");
  STAGE(4); STAGE(5); STAGE(6);
  asm volatile("s_waitcnt vmcnt(6)" ::: "memory");
  __builtin_amdgcn_s_barrier();

  for (int i = 0; i < ITERS; ++i) {
    const int s0 = 7 + (i << 3);
    const bool last = (i == ITERS - 1);
    // ---- K-tile 2i (buf 0) ----
    LDA_(0, 0); LDB_(0, 0); STAGE(s0 + 0);
    PHASE(DO_MFMA(0, 0));
    LDB_(0, 1);             STAGE(s0 + 1);
    PHASE(DO_MFMA(0, 1));
    LDA_(0, 1);             STAGE(s0 + 2);
    PHASE(DO_MFMA(1, 1));
                            STAGE(s0 + 3);
    if (last) asm volatile("s_waitcnt vmcnt(0)" ::: "memory");
    else      asm volatile("s_waitcnt vmcnt(6)" ::: "memory");
    PHASE(DO_MFMA(1, 0));
    // ---- K-tile 2i+1 (buf 1) ----
    LDA_(1, 0); LDB_(1, 0); STAGE(s0 + 4);
    PHASE(DO_MFMA(0, 0));
    LDB_(1, 1);             STAGE(s0 + 5);
    PHASE(DO_MFMA(0, 1));
    LDA_(1, 1);             STAGE(s0 + 6);
    PHASE(DO_MFMA(1, 1));
                            STAGE(s0 + 7);
    if (!last) asm volatile("s_waitcnt vmcnt(6)" ::: "memory");
    PHASE(DO_MFMA(1, 0));
  }

#undef STAGE
#undef LDA_
#undef LDB_
#undef DO_MFMA
#undef PHASE

  #pragma unroll
  for (int Mi = 0; Mi < 8; ++Mi) {
    #pragma unroll
    for (int Ni = 0; Ni < 4; ++Ni) {
      const int colg = n0 + wc * 64 + Ni * 16 + (lane & 15);
      float bv = 0.f;
      if (HAS_BIAS) bv = bias[(long)z * sBias + colg];
      #pragma unroll
      for (int r2 = 0; r2 < 4; ++r2) {
        const int rowg = m0 + wr * 128 + Mi * 16 + (lane >> 4) * 4 + r2;
        float v = acc[Mi][Ni][r2] + bv;
        if (RELU) v = fmaxf(v, 0.f);
        C[(long)rowg * N + colg] = f2bf(v);
      }
    }
  }
}

// ---------------- bf16 MFMA GEMM, 64x128 tile (G2) ----------
template<bool HAS_BIAS, bool RELU>
__global__ __launch_bounds__(256, 4)
void gemm_bm64(const unsigned short* __restrict__ A,
               const unsigned short* __restrict__ Bt,
               const float* __restrict__ bias,
               unsigned short* __restrict__ C,
               int N, int K, int nx, int ny, int GM,
               long sA, long sB, long sBias, long sC) {
  __shared__ unsigned short As[64 * 64];
  __shared__ unsigned short Bs[128 * 64];
  const int t = threadIdx.x;
  const int lane = t & 63;
  const int w = t >> 6, wr = w >> 1, wc = w & 1;

  const int nwg = gridDim.x;
  const int cpx = nwg >> 3;
  const int id = blockIdx.x;
  const int sw = (id & 7) * cpx + (id >> 3);
  const int z = sw / (nx * ny);
  const int rem = sw % (nx * ny);
  const int band = rem / (GM * nx);
  const int r = rem % (GM * nx);
  const int y = band * GM + (r % GM);
  const int x = r / GM;
  const int m0 = y * 64, n0 = x * 128;

  A += (long)z * sA;
  Bt += (long)z * sB;
  C += (long)z * sC;

  const int prow = lane >> 3;
  const int pcol = (lane & 7) * 8;

  f32x4 acc[2][4] = {};

  for (int kt = 0; kt < K; kt += 64) {
    __syncthreads();
    #pragma unroll
    for (int p = 0; p < 2; ++p) {
      const int rbase = p * 32 + w * 8;
      gload16(A + (long)(m0 + rbase + prow) * K + kt + pcol, As + rbase * 64);
    }
    #pragma unroll
    for (int p = 0; p < 4; ++p) {
      const int rbase = p * 32 + w * 8;
      gload16(Bt + (long)(n0 + rbase + prow) * K + kt + pcol, Bs + rbase * 64);
    }
    __syncthreads();
    #pragma unroll
    for (int ks = 0; ks < 2; ++ks) {
      bf16x8 af[2], bfr[4];
      #pragma unroll
      for (int mi = 0; mi < 2; ++mi) {
        const int row = wr * 32 + mi * 16 + (lane & 15);
        af[mi] = *(const bf16x8*)((const char*)As + row * 128 + ks * 64 + (lane >> 4) * 16);
      }
      #pragma unroll
      for (int ni = 0; ni < 4; ++ni) {
        const int row = wc * 64 + ni * 16 + (lane & 15);
        bfr[ni] = *(const bf16x8*)((const char*)Bs + row * 128 + ks * 64 + (lane >> 4) * 16);
      }
      #pragma unroll
      for (int mi = 0; mi < 2; ++mi)
        #pragma unroll
        for (int ni = 0; ni < 4; ++ni)
          acc[mi][ni] = __builtin_amdgcn_mfma_f32_16x16x32_bf16(af[mi], bfr[ni], acc[mi][ni], 0, 0, 0);
    }
  }

  #pragma unroll
  for (int mi = 0; mi < 2; ++mi) {
    #pragma unroll
    for (int ni = 0; ni < 4; ++ni) {
      const int colg = n0 + wc * 64 + ni * 16 + (lane & 15);
      float bv = 0.f;
      if (HAS_BIAS) bv = bias[(long)z * sBias + colg];
      #pragma unroll
      for (int r2 = 0; r2 < 4; ++r2) {
        const int rowg = m0 + wr * 32 + mi * 16 + (lane >> 4) * 4 + r2;
        float v = acc[mi][ni][r2] + bv;
        if (RELU) v = fmaxf(v, 0.f);
        C[(long)rowg * N + colg] = f2bf(v);
      }
    }
  }
}

// ---------------- fused clear heads, 64-row blocks ----------------
__global__ __launch_bounds__(256, 3)
void clear_fused(const unsigned short* __restrict__ emb,   // [8][M][256]
                 const unsigned short* __restrict__ Wc1T,  // [2048][256]
                 const float* __restrict__ bc1, const float* __restrict__ Wc2,
                 const float* __restrict__ bc2,
                 float* __restrict__ out, int M) {
  __shared__ unsigned short Ae[64 * 256];
  __shared__ unsigned short Bs[128 * 64];
  __shared__ float red[4][64];
  const int t = threadIdx.x;
  const int lane = t & 63;
  const int w = t >> 6;
  const int k = blockIdx.y;
  const int m0 = blockIdx.x * 64;
  const unsigned short* A = emb + ((long)k * M + m0) * 256;

  #pragma unroll
  for (int pass = 0; pass < 8; ++pass) {
    const int row = pass * 8 + (t >> 5);
    const int sc = t & 31;
    float4 v = *(const float4*)(A + (long)row * 256 + sc * 8);
    *(float4*)((char*)Ae + row * 512 + ((sc * 16) ^ ((row & 7) << 4))) = v;
  }

  float rsum[4][4] = {};

  for (int nt = 0; nt < 16; ++nt) {
    f32x4 acc[4][2] = {};
    for (int kt = 0; kt < 256; kt += 64) {
      __syncthreads();
      #pragma unroll
      for (int pass = 0; pass < 4; ++pass) {
        const int row = pass * 32 + (t >> 3);
        gload16(Wc1T + (long)(nt * 128 + row) * 256 + kt + (t & 7) * 8,
                Bs + row * 64 + (t & 7) * 8);
      }
      __syncthreads();
      #pragma unroll
      for (int ks = 0; ks < 2; ++ks) {
        bf16x8 af[4], bfr[2];
        #pragma unroll
        for (int mi = 0; mi < 4; ++mi) {
          const int row = mi * 16 + (lane & 15);
          const int ce = kt + ks * 32 + (lane >> 4) * 8;
          af[mi] = *(const bf16x8*)((const char*)Ae + row * 512 + ((ce * 2) ^ ((row & 7) << 4)));
        }
        #pragma unroll
        for (int ni = 0; ni < 2; ++ni) {
          const int row = w * 32 + ni * 16 + (lane & 15);
          bfr[ni] = *(const bf16x8*)((const char*)Bs + row * 128 + ks * 64 + (lane >> 4) * 16);
        }
        #pragma unroll
        for (int mi = 0; mi < 4; ++mi)
          #pragma unroll
          for (int ni = 0; ni < 2; ++ni)
            acc[mi][ni] = __builtin_amdgcn_mfma_f32_16x16x32_bf16(af[mi], bfr[ni], acc[mi][ni], 0, 0, 0);
      }
    }
    #pragma unroll
    for (int mi = 0; mi < 4; ++mi) {
      #pragma unroll
      for (int ni = 0; ni < 2; ++ni) {
        const int col = nt * 128 + w * 32 + ni * 16 + (lane & 15);
        const float bv = bc1[col], wv = Wc2[col];
        #pragma unroll
        for (int r = 0; r < 4; ++r)
          rsum[mi][r] += fmaxf(acc[mi][ni][r] + bv, 0.f) * wv;
      }
    }
  }

  #pragma unroll
  for (int off = 1; off < 16; off <<= 1)
    #pragma unroll
    for (int mi = 0; mi < 4; ++mi)
      #pragma unroll
      for (int r = 0; r < 4; ++r)
        rsum[mi][r] += __shfl_xor(rsum[mi][r], off, 64);
  if ((lane & 15) == 0) {
    #pragma unroll
    for (int mi = 0; mi < 4; ++mi)
      #pragma unroll
      for (int r = 0; r < 4; ++r)
        red[w][mi * 16 + (lane >> 4) * 4 + r] = rsum[mi][r];
  }
  __syncthreads();
  if (t < 64)
    out[(long)(m0 + t) * 64 + 56 + k] =
        red[0][t] + red[1][t] + red[2][t] + red[3][t] + bc2[0];
}

// ---------------- pairwise reduce: on[p,b] ----------------
// bon1 is folded into V at staging time (c0=1 pass is uniformly the V half),
// so the 56x2048 inner loop is add+max+fma (3 ops) instead of 4 + 2 extra loads.
__global__ __launch_bounds__(256)
void pair_reduce_kernel(const unsigned short* __restrict__ UVT,  // [8][Mc][4096]
                        const float* __restrict__ bon1, const float* __restrict__ Won2,
                        const float* __restrict__ bon2,
                        float* __restrict__ out, int Mc) {
  __shared__ unsigned short uv[8 * 4096];
  const int b = blockIdx.x, t = threadIdx.x;
  const long kstride = (long)Mc * 4096;
  const unsigned short* src = UVT + (long)b * 4096;

  float4 ba = *(const float4*)(bon1 + t * 8);
  float4 bb = *(const float4*)(bon1 + t * 8 + 4);
  const float bsv[8] = {ba.x, ba.y, ba.z, ba.w, bb.x, bb.y, bb.z, bb.w};

  for (int k = 0; k < 8; ++k) {
    const unsigned short* s = src + (long)k * kstride;
    {  // U half: raw copy
      const int c = t;
      const int byte = k * 8192 + ((c * 16) ^ ((k & 7) << 4));
      *(float4*)((char*)uv + byte) = *(const float4*)(s + c * 8);
    }
    {  // V half: add bon1, re-encode bf16
      const int c = 256 + t;
      bf16x8 v = *(const bf16x8*)(s + c * 8);
      u16x8 o;
      #pragma unroll
      for (int e = 0; e < 8; ++e)
        o[e] = f2bf(bf2f(v[e]) + bsv[e]);
      const int byte = k * 8192 + ((c * 16) ^ ((k & 7) << 4));
      *(u16x8*)((char*)uv + byte) = o;
    }
  }
  __syncthreads();
  const int p = t & 63, q = t >> 6;
  float acc = 0.f;
  if (p < 56) {
    const int i = p / 7;
    const int jj = p % 7;
    const int j = jj + (jj >= i);
    const char* ubase = (const char*)uv + i * 8192;
    const char* vbase = (const char*)uv + j * 8192;
    const int uswz = (i & 7) << 4, vswz = (j & 7) << 4;
    for (int it = 0; it < 64; ++it) {
      const int h = q * 512 + it * 8;
      bf16x8 uu = *(const bf16x8*)(ubase + ((h * 2) ^ uswz));
      bf16x8 vv = *(const bf16x8*)(vbase + ((4096 + h * 2) ^ vswz));
      float4 wa = *(const float4*)(Won2 + h);
      float4 wb = *(const float4*)(Won2 + h + 4);
      float wv[8] = {wa.x, wa.y, wa.z, wa.w, wb.x, wb.y, wb.z, wb.w};
      #pragma unroll
      for (int e = 0; e < 8; ++e) {
        float xv = bf2f(uu[e]) + bf2f(vv[e]);
        acc += fmaxf(xv, 0.f) * wv[e];
      }
    }
  }
  __syncthreads();
  float* red = (float*)uv;
  red[q * 64 + p] = acc;
  __syncthreads();
  if (t < 56)
    out[(long)b * 64 + t] = red[t] + red[64 + t] + red[128 + t] + red[192 + t] + bon2[0];
}

extern "C" void kernel_launch(void* const* d_in, const int* in_sizes, int n_in,
                              void* d_out, int out_size, void* d_ws, size_t ws_size,
                              hipStream_t stream) {
  (void)in_sizes; (void)n_in; (void)out_size;
  const float* input = (const float*)d_in[0];
  const float* W1    = (const float*)d_in[1];
  const float* b1    = (const float*)d_in[2];
  const float* W2    = (const float*)d_in[3];
  const float* b2    = (const float*)d_in[4];
  const float* Won1  = (const float*)d_in[5];
  const float* bon1  = (const float*)d_in[6];
  const float* Won2  = (const float*)d_in[7];
  const float* bon2  = (const float*)d_in[8];
  const float* Wc1   = (const float*)d_in[9];
  const float* bc1   = (const float*)d_in[10];
  const float* Wc2   = (const float*)d_in[11];
  const float* bc2   = (const float*)d_in[12];
  float* out = (float*)d_out;

  char* base = (char*)d_ws;
  unsigned short* inputb = (unsigned short*)(base);                  //   8 MB
  unsigned short* W1T    = (unsigned short*)(base + 8388608L);       //  32 MB [8][2048][1024]
  unsigned short* W2T    = (unsigned short*)(base + 41943040L);      //   8 MB [8][256][2048]
  unsigned short* WcatT  = (unsigned short*)(base + 50331648L);      //   2 MB [4096][256]
  unsigned short* Wc1T   = (unsigned short*)(base + 52428800L);      //   1 MB [2048][256]
  unsigned short* hbuf   = (unsigned short*)(base + 53477376L);      // 128 MB [8][4096][2048]
  unsigned short* embbuf = (unsigned short*)(base + 187695104L);     //  16 MB [8][4096][256]
  unsigned short* UVTbuf = (unsigned short*)(base + 204472320L);     // Mc*64KB [8][Mc][4096]

  int Mc = 512;
  const int mopts[3] = {4096, 2048, 1024};
  for (int oi = 0; oi < 3; ++oi) {
    if (204472320L + (long)mopts[oi] * 65536L <= (long)ws_size) { Mc = mopts[oi]; break; }
  }
  const int nc = 4096 / Mc;

  prep_kernel<<<dim3(24064), 256, 0, stream>>>(input, W1, W2, Won1, Wc1,
                                               inputb, W1T, W2T, WcatT, Wc1T);

  // G1 full-batch, 8-phase 256^2: h[k] = relu(input @ W1[k] + b1[k])
  gemm256<true, true><<<dim3(8 * 16 * 8), 512, 0, stream>>>(
      inputb, W1T, b1, hbuf, 2048, 1024, 8, 16, 4,
      0L, (long)2048 * 1024, 2048L, (long)4096 * 2048);

  // G2 full-batch (64x128 tiles): emb[k] = h[k] @ W2[k] + b2[k]
  gemm_bm64<true, false><<<dim3(2 * 64 * 8), 256, 0, stream>>>(
      hbuf, W2T, b2, embbuf, 256, 2048, 2, 64, 4,
      (long)4096 * 2048, (long)256 * 2048, 256L, (long)4096 * 256);

  // clear heads full-batch
  clear_fused<<<dim3(64, 8), 256, 0, stream>>>(embbuf, Wc1T, bc1, Wc2, bc2, out, 4096);

  // G3 (8-phase 256^2, K=256) + pair reduce, chunked over b
  for (int cc = 0; cc < nc; ++cc) {
    const long b0 = (long)cc * Mc;
    const int nyc = Mc / 256;
    const int GM3 = (nyc % 4 == 0) ? 4 : ((nyc % 2 == 0) ? 2 : 1);
    gemm256<false, false><<<dim3(16 * nyc * 8), 512, 0, stream>>>(
        embbuf + b0 * 256, WcatT, nullptr, UVTbuf, 4096, 256, 16, nyc, GM3,
        (long)4096 * 256, 0L, 0L, (long)Mc * 4096);
    pair_reduce_kernel<<<dim3(Mc), 256, 0, stream>>>(
        UVTbuf, bon1, Won2, bon2, out + b0 * 64, Mc);
  }
}

// Round 10
// 582.964 us; speedup vs baseline: 1.3211x; 1.0318x over previous
//
#include <hip/hip_runtime.h>

typedef __attribute__((ext_vector_type(8))) short bf16x8;
typedef __attribute__((ext_vector_type(4))) float f32x4;
typedef __attribute__((ext_vector_type(8))) unsigned short u16x8;

__device__ __forceinline__ float bf2f(short s) {
  unsigned u = ((unsigned)(unsigned short)s) << 16;
  return __builtin_bit_cast(float, u);
}
__device__ __forceinline__ unsigned short f2bf(float f) {
  unsigned u = __builtin_bit_cast(unsigned, f);
  u = (u + 0x7fffu + ((u >> 16) & 1u)) >> 16;
  return (unsigned short)u;
}
__device__ __forceinline__ void gload16(const unsigned short* g, unsigned short* l) {
  __builtin_amdgcn_global_load_lds(
      (const __attribute__((address_space(1))) void*)g,
      (__attribute__((address_space(3))) void*)l, 16, 0, 0);
}

// ---------------- merged prep: input cvt + all 5 weight transposes ----------------
__global__ __launch_bounds__(256)
void prep_kernel(const float* __restrict__ input, const float* __restrict__ W1,
                 const float* __restrict__ W2, const float* __restrict__ Won1,
                 const float* __restrict__ Wc1,
                 unsigned short* __restrict__ inputb, unsigned short* __restrict__ W1T,
                 unsigned short* __restrict__ W2T, unsigned short* __restrict__ WcatT,
                 unsigned short* __restrict__ Wc1T) {
  int bid = blockIdx.x;
  const int t = threadIdx.x;
  if (bid < 2048) {  // cvt input -> bf16 (4096x1024)
    long i = ((long)bid * 256 + t) * 8;
    float4 a = *(const float4*)(input + i);
    float4 b = *(const float4*)(input + i + 4);
    u16x8 o;
    o[0] = f2bf(a.x); o[1] = f2bf(a.y); o[2] = f2bf(a.z); o[3] = f2bf(a.w);
    o[4] = f2bf(b.x); o[5] = f2bf(b.y); o[6] = f2bf(b.z); o[7] = f2bf(b.w);
    *(u16x8*)(inputb + i) = o;
    return;
  }
  bid -= 2048;
  const float* src; unsigned short* dst;
  int R, C, tilesX, tilesY; long sb, db;
  if (bid < 16384) {                    // W1[k][1024,2048] -> W1T[k][2048,1024]
    src = W1; dst = W1T; R = 1024; C = 2048; tilesX = 64; tilesY = 32;
    sb = 2097152; db = 2097152;
  } else if ((bid -= 16384) < 4096) {   // W2[k][2048,256] -> W2T[k][256,2048]
    src = W2; dst = W2T; R = 2048; C = 256; tilesX = 8; tilesY = 64;
    sb = 524288; db = 524288;
  } else if ((bid -= 4096) < 512) {     // Won1 top half -> WcatT[0:2048]
    src = Won1; dst = WcatT; R = 256; C = 2048; tilesX = 64; tilesY = 8;
    sb = 0; db = 0;
  } else if ((bid -= 512) < 512) {      // Won1 bottom half -> WcatT[2048:4096]
    src = Won1 + 524288; dst = WcatT + (long)2048 * 256;
    R = 256; C = 2048; tilesX = 64; tilesY = 8; sb = 0; db = 0;
  } else {                              // Wc1 -> Wc1T[2048,256]
    bid -= 512;
    src = Wc1; dst = Wc1T; R = 256; C = 2048; tilesX = 64; tilesY = 8;
    sb = 0; db = 0;
  }
  const int x = bid % tilesX;
  const int rem = bid / tilesX;
  const int y = rem % tilesY;
  const int z = rem / tilesY;
  src += (long)z * sb;
  dst += (long)z * db;
  __shared__ float tile[32][33];
  const int tx = t & 31, ty = t >> 5;
  const int bx = x * 32, by = y * 32;
  #pragma unroll
  for (int i = ty; i < 32; i += 8)
    tile[i][tx] = src[(long)(by + i) * C + bx + tx];
  __syncthreads();
  #pragma unroll
  for (int i = ty; i < 32; i += 8)
    dst[(long)(bx + i) * R + by + tx] = f2bf(tile[tx][i]);
}

// ---------------- 8-phase 256x256 GEMM (T2+T3+T4+T5): C = A[M,K] @ Bt[N,K]^T ----
// 512 threads, 8 waves (2M x 4N), BK=64. ldc = C row stride (b-major layouts).
// Stage-slot safety: every STAGE targets a region whose reads were drained by a
// CLOSED phase (lgkmcnt(0) + barrier) before the stage issues. Verified per-slot.
template<bool HAS_BIAS, bool RELU>
__global__ __launch_bounds__(512, 1)
void gemm256(const unsigned short* __restrict__ A,
             const unsigned short* __restrict__ Bt,
             const float* __restrict__ bias,
             unsigned short* __restrict__ C,
             int N, int K, int ldc, int nx, int ny, int GM,
             long sA, long sB, long sBias, long sC) {
  __shared__ unsigned short lds[65536];  // 128KB
  const int t = threadIdx.x;
  const int lane = t & 63;
  const int w = t >> 6, wr = w >> 2, wc = w & 3;

  const int nwg = gridDim.x;
  const int cpx = nwg >> 3;
  const int id = blockIdx.x;
  const int sw = (id & 7) * cpx + (id >> 3);
  const int z = sw / (nx * ny);
  const int rem = sw % (nx * ny);
  const int band = rem / (GM * nx);
  const int rr = rem % (GM * nx);
  const int y = band * GM + (rr % GM);
  const int x = rr / GM;
  const int m0 = y * 256, n0 = x * 256;

  A += (long)z * sA;
  Bt += (long)z * sB;
  C += (long)z * sC;

  const int NH = K >> 4;
  const int ITERS = K >> 7;

  const int sr0 = t >> 3;
  const int sc0 = (t & 7) * 16;
  const int cks0 = (((lane >> 4) * 16)) ^ ((lane & 7) << 4);
  const int cks1 = (64 + ((lane >> 4) * 16)) ^ ((lane & 7) << 4);
  const int aoff = wr * 16384 + (lane & 15) * 128;
  const int boff = 32768 + (wc >> 1) * 16384 + ((wc & 1) * 64 + (lane & 15)) * 128;

  f32x4 acc[8][4] = {};
  bf16x8 af[4][2];
  bf16x8 bfr[2][2][2];

#define STAGE(S) do { if ((S) < NH) {                                          \
    const int kt_ = (S) >> 2, slot_ = (S) & 3;                                 \
    const int base_ = ((kt_ & 1) << 16) + ((slot_ < 2) ? 32768 : 0)            \
                      + ((slot_ & 1) << 14);                                   \
    const unsigned short* gb_;                                                 \
    _Pragma("unroll")                                                          \
    for (int j_ = 0; j_ < 2; ++j_) {                                           \
      const int r_ = sr0 + j_ * 64;                                            \
      const int yc_ = sc0 ^ ((r_ & 7) << 4);                                   \
      if (slot_ < 2)                                                           \
        gb_ = Bt + (long)(n0 + (slot_ & 1) * 128 + r_) * K + kt_ * 64 + (yc_ >> 1); \
      else                                                                     \
        gb_ = A + (long)(m0 + (slot_ & 1) * 128 + r_) * K + kt_ * 64 + (yc_ >> 1);  \
      gload16(gb_, lds + (base_ >> 1) + j_ * 4096 + t * 8);                    \
    } } } while (0)

#define LDA_(BUF, HM) do { _Pragma("unroll")                                   \
    for (int mi_ = 0; mi_ < 4; ++mi_) {                                        \
      af[mi_][0] = *(const bf16x8*)((const char*)lds + (BUF) * 65536 + aoff + ((HM) * 4 + mi_) * 2048 + cks0); \
      af[mi_][1] = *(const bf16x8*)((const char*)lds + (BUF) * 65536 + aoff + ((HM) * 4 + mi_) * 2048 + cks1); \
    } } while (0)

#define LDB_(BUF, HN) do { _Pragma("unroll")                                   \
    for (int ni_ = 0; ni_ < 2; ++ni_) {                                        \
      bfr[HN][ni_][0] = *(const bf16x8*)((const char*)lds + (BUF) * 65536 + boff + ((HN) * 2 + ni_) * 2048 + cks0); \
      bfr[HN][ni_][1] = *(const bf16x8*)((const char*)lds + (BUF) * 65536 + boff + ((HN) * 2 + ni_) * 2048 + cks1); \
    } } while (0)

#define DO_MFMA(HM, HN) do { _Pragma("unroll")                                 \
    for (int mi_ = 0; mi_ < 4; ++mi_) { _Pragma("unroll")                      \
      for (int ni_ = 0; ni_ < 2; ++ni_) { _Pragma("unroll")                    \
        for (int ks_ = 0; ks_ < 2; ++ks_)                                      \
          acc[(HM) * 4 + mi_][(HN) * 2 + ni_] =                                \
            __builtin_amdgcn_mfma_f32_16x16x32_bf16(af[mi_][ks_], bfr[HN][ni_][ks_], \
                acc[(HM) * 4 + mi_][(HN) * 2 + ni_], 0, 0, 0);                 \
    } } } while (0)

#define PHASE(MB) do {                                                         \
    __builtin_amdgcn_s_barrier();                                              \
    asm volatile("s_waitcnt lgkmcnt(0)" ::: "memory");                         \
    __builtin_amdgcn_sched_barrier(0);                                         \
    __builtin_amdgcn_s_setprio(1);                                             \
    MB;                                                                        \
    __builtin_amdgcn_s_setprio(0);                                             \
    __builtin_amdgcn_s_barrier();                                              \
  } while (0)

  STAGE(0); STAGE(1); STAGE(2); STAGE(3);
  asm volatile("s_waitcnt vmcnt(4)" ::: "memory");
  STAGE(4); STAGE(5); STAGE(6);
  asm volatile("s_waitcnt vmcnt(6)" ::: "memory");
  __builtin_amdgcn_s_barrier();

  for (int i = 0; i < ITERS; ++i) {
    const int s0 = 7 + (i << 3);
    const bool last = (i == ITERS - 1);
    // ---- K-tile 2i (buf 0) ----
    LDA_(0, 0); LDB_(0, 0); STAGE(s0 + 0);
    asm volatile("s_waitcnt lgkmcnt(8)" ::: "memory");
    PHASE(DO_MFMA(0, 0));
    LDB_(0, 1);             STAGE(s0 + 1);
    PHASE(DO_MFMA(0, 1));
    LDA_(0, 1);             STAGE(s0 + 2);
    PHASE(DO_MFMA(1, 1));
                            STAGE(s0 + 3);
    if (last) asm volatile("s_waitcnt vmcnt(0)" ::: "memory");
    else      asm volatile("s_waitcnt vmcnt(6)" ::: "memory");
    PHASE(DO_MFMA(1, 0));
    // ---- K-tile 2i+1 (buf 1) ----
    LDA_(1, 0); LDB_(1, 0); STAGE(s0 + 4);
    asm volatile("s_waitcnt lgkmcnt(8)" ::: "memory");
    PHASE(DO_MFMA(0, 0));
    LDB_(1, 1);             STAGE(s0 + 5);
    PHASE(DO_MFMA(0, 1));
    LDA_(1, 1);             STAGE(s0 + 6);
    PHASE(DO_MFMA(1, 1));
                            STAGE(s0 + 7);
    if (!last) asm volatile("s_waitcnt vmcnt(6)" ::: "memory");
    PHASE(DO_MFMA(1, 0));
  }

#undef STAGE
#undef LDA_
#undef LDB_
#undef DO_MFMA
#undef PHASE

  #pragma unroll
  for (int Mi = 0; Mi < 8; ++Mi) {
    #pragma unroll
    for (int Ni = 0; Ni < 4; ++Ni) {
      const int colg = n0 + wc * 64 + Ni * 16 + (lane & 15);
      float bv = 0.f;
      if (HAS_BIAS) bv = bias[(long)z * sBias + colg];
      #pragma unroll
      for (int r2 = 0; r2 < 4; ++r2) {
        const int rowg = m0 + wr * 128 + Mi * 16 + (lane >> 4) * 4 + r2;
        float v = acc[Mi][Ni][r2] + bv;
        if (RELU) v = fmaxf(v, 0.f);
        C[(long)rowg * ldc + colg] = f2bf(v);
      }
    }
  }
}

// ---------------- 8-phase 128x256 GEMM — FIXED schedule ----------------
// 512 threads, 8 waves (2M x 4N), wave tile 64x64, 2 phases/K-tile (16 MFMA).
// LDS 96KB = 2 buf x {B0 16K, B1 16K, A0 8K, A1 8K}.
// Stage slots (derived so each stage lands >=1 CLOSED phase after its region's
// last read): pre-A:{Bhi buf1 k+1}, pre-B:{Blo,Alo,Ahi buf0 k+2},
// pre-C:{Bhi buf0 k+2}, pre-D:{Blo,Alo,Ahi buf1 k+3}.
// Consumption->vmcnt: every producer is exactly 6 loads back => uniform
// vmcnt(6) before each phase; vmcnt(0) at phases B/C on the last iteration.
template<bool HAS_BIAS, bool RELU>
__global__ __launch_bounds__(512, 1)
void gemm_bm128(const unsigned short* __restrict__ A,
                const unsigned short* __restrict__ Bt,
                const float* __restrict__ bias,
                unsigned short* __restrict__ C,
                int N, int K, int nx, int ny, int GM,
                long sA, long sB, long sBias, long sC) {
  __shared__ unsigned short lds[49152];  // 96KB
  const int t = threadIdx.x;
  const int lane = t & 63;
  const int w = t >> 6, wr = w >> 2, wc = w & 3;

  const int nwg = gridDim.x;
  const int cpx = nwg >> 3;
  const int id = blockIdx.x;
  const int sw = (id & 7) * cpx + (id >> 3);
  const int z = sw / (nx * ny);
  const int rem = sw % (nx * ny);
  const int band = rem / (GM * nx);
  const int rr = rem % (GM * nx);
  const int y = band * GM + (rr % GM);
  const int x = rr / GM;
  const int m0 = y * 128, n0 = x * 256;

  A += (long)z * sA;
  Bt += (long)z * sB;
  C += (long)z * sC;

  const int NH = K >> 4;
  const int ITERS = K >> 7;

  const int sr0 = t >> 3;
  const int sc0 = (t & 7) * 16;
  const int cks0 = (((lane >> 4) * 16)) ^ ((lane & 7) << 4);
  const int cks1 = (64 + ((lane >> 4) * 16)) ^ ((lane & 7) << 4);
  const int abase = 32768 + wr * 8192 + (lane & 15) * 128;
  const int bbase = (wc >> 1) * 16384 + ((wc & 1) * 64 + (lane & 15)) * 128;

  f32x4 acc[4][4] = {};
  bf16x8 af[4][2];
  bf16x8 bfr[2][2];

#define STAGE(S) do { if ((S) < NH) {                                          \
    const int kt_ = (S) >> 2, slot_ = (S) & 3;                                 \
    const int bufb_ = (kt_ & 1) * 49152;                                       \
    if (slot_ < 2) {                                                           \
      _Pragma("unroll")                                                        \
      for (int j_ = 0; j_ < 2; ++j_) {                                         \
        const int r_ = sr0 + j_ * 64;                                          \
        const int yc_ = sc0 ^ ((r_ & 7) << 4);                                 \
        gload16(Bt + (long)(n0 + slot_ * 128 + r_) * K + kt_ * 64 + (yc_ >> 1),\
                lds + ((bufb_ + slot_ * 16384 + j_ * 8192) >> 1) + t * 8);     \
      }                                                                        \
    } else {                                                                   \
      const int yc_ = sc0 ^ ((sr0 & 7) << 4);                                  \
      gload16(A + (long)(m0 + (slot_ & 1) * 64 + sr0) * K + kt_ * 64 + (yc_ >> 1), \
              lds + ((bufb_ + 32768 + (slot_ & 1) * 8192) >> 1) + t * 8);      \
    } } } while (0)

#define LDA_(BUF) do { _Pragma("unroll")                                       \
    for (int mi_ = 0; mi_ < 4; ++mi_) {                                        \
      af[mi_][0] = *(const bf16x8*)((const char*)lds + (BUF) * 49152 + abase + mi_ * 2048 + cks0); \
      af[mi_][1] = *(const bf16x8*)((const char*)lds + (BUF) * 49152 + abase + mi_ * 2048 + cks1); \
    } } while (0)

#define LDB_(BUF, HN) do { _Pragma("unroll")                                   \
    for (int ni_ = 0; ni_ < 2; ++ni_) {                                        \
      bfr[ni_][0] = *(const bf16x8*)((const char*)lds + (BUF) * 49152 + bbase + ((HN) * 2 + ni_) * 2048 + cks0); \
      bfr[ni_][1] = *(const bf16x8*)((const char*)lds + (BUF) * 49152 + bbase + ((HN) * 2 + ni_) * 2048 + cks1); \
    } } while (0)

#define DO_MFMA(HN) do { _Pragma("unroll")                                     \
    for (int mi_ = 0; mi_ < 4; ++mi_) { _Pragma("unroll")                      \
      for (int ni_ = 0; ni_ < 2; ++ni_) { _Pragma("unroll")                    \
        for (int ks_ = 0; ks_ < 2; ++ks_)                                      \
          acc[mi_][(HN) * 2 + ni_] =                                           \
            __builtin_amdgcn_mfma_f32_16x16x32_bf16(af[mi_][ks_], bfr[ni_][ks_], \
                acc[mi_][(HN) * 2 + ni_], 0, 0, 0);                            \
    } } } while (0)

#define PHASE(MB) do {                                                         \
    __builtin_amdgcn_s_barrier();                                              \
    asm volatile("s_waitcnt lgkmcnt(0)" ::: "memory");                         \
    __builtin_amdgcn_sched_barrier(0);                                         \
    __builtin_amdgcn_s_setprio(1);                                             \
    MB;                                                                        \
    __builtin_amdgcn_s_setprio(0);                                             \
    __builtin_amdgcn_s_barrier();                                              \
  } while (0)

  // prologue mimics steady-state issue order:
  // K0 {Blo,Alo,Ahi,Bhi} + K1 {Blo,Alo,Ahi}; vmcnt(6) => K0 fully landed.
  STAGE(0); STAGE(2); STAGE(3); STAGE(1);
  STAGE(4); STAGE(6); STAGE(7);
  asm volatile("s_waitcnt vmcnt(6)" ::: "memory");
  __builtin_amdgcn_s_barrier();

  for (int i = 0; i < ITERS; ++i) {
    const int s0 = i << 3;  // K-tile 2i halves = s0+0..3; 2i+1 = s0+4..7
    const bool last = (i == ITERS - 1);
    // ---- phase A: K-tile 2i (buf0), HN0 ----
    LDA_(0); LDB_(0, 0);
    STAGE(s0 + 5);                         // Bhi buf1 (K2i+1)
    asm volatile("s_waitcnt lgkmcnt(8)" ::: "memory");
    asm volatile("s_waitcnt vmcnt(6)" ::: "memory");   // Bhi buf0(K2i) landed
    PHASE(DO_MFMA(0));
    // ---- phase B: K-tile 2i, HN1 ----
    LDB_(0, 1);
    STAGE(s0 + 8); STAGE(s0 + 10); STAGE(s0 + 11);  // Blo,Alo,Ahi buf0 (K2i+2)
    if (last) asm volatile("s_waitcnt vmcnt(0)" ::: "memory");
    else      asm volatile("s_waitcnt vmcnt(6)" ::: "memory");  // A+Blo buf1(K2i+1) landed
    PHASE(DO_MFMA(1));
    // ---- phase C: K-tile 2i+1 (buf1), HN0 ----
    LDA_(1); LDB_(1, 0);
    STAGE(s0 + 9);                         // Bhi buf0 (K2i+2)
    asm volatile("s_waitcnt lgkmcnt(8)" ::: "memory");
    if (last) asm volatile("s_waitcnt vmcnt(0)" ::: "memory");
    else      asm volatile("s_waitcnt vmcnt(6)" ::: "memory");  // Bhi buf1(K2i+1) landed
    PHASE(DO_MFMA(0));
    // ---- phase D: K-tile 2i+1, HN1 ----
    LDB_(1, 1);
    STAGE(s0 + 12); STAGE(s0 + 14); STAGE(s0 + 15);  // Blo,Alo,Ahi buf1 (K2i+3)
    if (!last) asm volatile("s_waitcnt vmcnt(6)" ::: "memory"); // buf0(K2i+2) landed
    PHASE(DO_MFMA(1));
  }

#undef STAGE
#undef LDA_
#undef LDB_
#undef DO_MFMA
#undef PHASE

  #pragma unroll
  for (int mi = 0; mi < 4; ++mi) {
    #pragma unroll
    for (int ni = 0; ni < 4; ++ni) {
      const int colg = n0 + wc * 64 + ni * 16 + (lane & 15);
      float bv = 0.f;
      if (HAS_BIAS) bv = bias[(long)z * sBias + colg];
      #pragma unroll
      for (int r2 = 0; r2 < 4; ++r2) {
        const int rowg = m0 + wr * 64 + mi * 16 + (lane >> 4) * 4 + r2;
        float v = acc[mi][ni][r2] + bv;
        if (RELU) v = fmaxf(v, 0.f);
        C[(long)rowg * N + colg] = f2bf(v);
      }
    }
  }
}

// ---------------- fused clear heads, 64-row blocks ----------------
__global__ __launch_bounds__(256, 3)
void clear_fused(const unsigned short* __restrict__ emb,   // [8][M][256]
                 const unsigned short* __restrict__ Wc1T,  // [2048][256]
                 const float* __restrict__ bc1, const float* __restrict__ Wc2,
                 const float* __restrict__ bc2,
                 float* __restrict__ out, int M) {
  __shared__ unsigned short Ae[64 * 256];
  __shared__ unsigned short Bs[128 * 64];
  __shared__ float red[4][64];
  const int t = threadIdx.x;
  const int lane = t & 63;
  const int w = t >> 6;
  const int k = blockIdx.y;
  const int m0 = blockIdx.x * 64;
  const unsigned short* A = emb + ((long)k * M + m0) * 256;

  #pragma unroll
  for (int pass = 0; pass < 8; ++pass) {
    const int row = pass * 8 + (t >> 5);
    const int sc = t & 31;
    float4 v = *(const float4*)(A + (long)row * 256 + sc * 8);
    *(float4*)((char*)Ae + row * 512 + ((sc * 16) ^ ((row & 7) << 4))) = v;
  }

  float rsum[4][4] = {};

  for (int nt = 0; nt < 16; ++nt) {
    f32x4 acc[4][2] = {};
    for (int kt = 0; kt < 256; kt += 64) {
      __syncthreads();
      #pragma unroll
      for (int pass = 0; pass < 4; ++pass) {
        const int row = pass * 32 + (t >> 3);
        gload16(Wc1T + (long)(nt * 128 + row) * 256 + kt + (t & 7) * 8,
                Bs + row * 64 + (t & 7) * 8);
      }
      __syncthreads();
      #pragma unroll
      for (int ks = 0; ks < 2; ++ks) {
        bf16x8 af[4], bfr[2];
        #pragma unroll
        for (int mi = 0; mi < 4; ++mi) {
          const int row = mi * 16 + (lane & 15);
          const int ce = kt + ks * 32 + (lane >> 4) * 8;
          af[mi] = *(const bf16x8*)((const char*)Ae + row * 512 + ((ce * 2) ^ ((row & 7) << 4)));
        }
        #pragma unroll
        for (int ni = 0; ni < 2; ++ni) {
          const int row = w * 32 + ni * 16 + (lane & 15);
          bfr[ni] = *(const bf16x8*)((const char*)Bs + row * 128 + ks * 64 + (lane >> 4) * 16);
        }
        #pragma unroll
        for (int mi = 0; mi < 4; ++mi)
          #pragma unroll
          for (int ni = 0; ni < 2; ++ni)
            acc[mi][ni] = __builtin_amdgcn_mfma_f32_16x16x32_bf16(af[mi], bfr[ni], acc[mi][ni], 0, 0, 0);
      }
    }
    #pragma unroll
    for (int mi = 0; mi < 4; ++mi) {
      #pragma unroll
      for (int ni = 0; ni < 2; ++ni) {
        const int col = nt * 128 + w * 32 + ni * 16 + (lane & 15);
        const float bv = bc1[col], wv = Wc2[col];
        #pragma unroll
        for (int r = 0; r < 4; ++r)
          rsum[mi][r] += fmaxf(acc[mi][ni][r] + bv, 0.f) * wv;
      }
    }
  }

  #pragma unroll
  for (int off = 1; off < 16; off <<= 1)
    #pragma unroll
    for (int mi = 0; mi < 4; ++mi)
      #pragma unroll
      for (int r = 0; r < 4; ++r)
        rsum[mi][r] += __shfl_xor(rsum[mi][r], off, 64);
  if ((lane & 15) == 0) {
    #pragma unroll
    for (int mi = 0; mi < 4; ++mi)
      #pragma unroll
      for (int r = 0; r < 4; ++r)
        red[w][mi * 16 + (lane >> 4) * 4 + r] = rsum[mi][r];
  }
  __syncthreads();
  if (t < 64)
    out[(long)(m0 + t) * 64 + 56 + k] =
        red[0][t] + red[1][t] + red[2][t] + red[3][t] + bc2[0];
}

// ---------------- pairwise reduce: on[p,b] ----------------
// UVT is b-major: [Mc][8][4096] -> one contiguous 64KB strip per b.
__global__ __launch_bounds__(256)
void pair_reduce_kernel(const unsigned short* __restrict__ UVT,
                        const float* __restrict__ bon1, const float* __restrict__ Won2,
                        const float* __restrict__ bon2,
                        float* __restrict__ out, int Mc) {
  __shared__ unsigned short uv[8 * 4096];
  const int b = blockIdx.x, t = threadIdx.x;
  const unsigned short* src = UVT + (long)b * 32768;

  float4 ba = *(const float4*)(bon1 + t * 8);
  float4 bb = *(const float4*)(bon1 + t * 8 + 4);
  const float bsv[8] = {ba.x, ba.y, ba.z, ba.w, bb.x, bb.y, bb.z, bb.w};

  for (int k = 0; k < 8; ++k) {
    const unsigned short* s = src + (long)k * 4096;
    {  // U half: raw copy
      const int c = t;
      const int byte = k * 8192 + ((c * 16) ^ ((k & 7) << 4));
      *(float4*)((char*)uv + byte) = *(const float4*)(s + c * 8);
    }
    {  // V half: add bon1, re-encode bf16
      const int c = 256 + t;
      bf16x8 v = *(const bf16x8*)(s + c * 8);
      u16x8 o;
      #pragma unroll
      for (int e = 0; e < 8; ++e)
        o[e] = f2bf(bf2f(v[e]) + bsv[e]);
      const int byte = k * 8192 + ((c * 16) ^ ((k & 7) << 4));
      *(u16x8*)((char*)uv + byte) = o;
    }
  }
  __syncthreads();
  const int p = t & 63, q = t >> 6;
  float acc = 0.f;
  if (p < 56) {
    const int i = p / 7;
    const int jj = p % 7;
    const int j = jj + (jj >= i);
    const char* ubase = (const char*)uv + i * 8192;
    const char* vbase = (const char*)uv + j * 8192;
    const int uswz = (i & 7) << 4, vswz = (j & 7) << 4;
    for (int it = 0; it < 64; ++it) {
      const int h = q * 512 + it * 8;
      bf16x8 uu = *(const bf16x8*)(ubase + ((h * 2) ^ uswz));
      bf16x8 vv = *(const bf16x8*)(vbase + ((4096 + h * 2) ^ vswz));
      float4 wa = *(const float4*)(Won2 + h);
      float4 wb = *(const float4*)(Won2 + h + 4);
      float wv[8] = {wa.x, wa.y, wa.z, wa.w, wb.x, wb.y, wb.z, wb.w};
      #pragma unroll
      for (int e = 0; e < 8; ++e) {
        float xv = bf2f(uu[e]) + bf2f(vv[e]);
        acc += fmaxf(xv, 0.f) * wv[e];
      }
    }
  }
  __syncthreads();
  float* red = (float*)uv;
  red[q * 64 + p] = acc;
  __syncthreads();
  if (t < 56)
    out[(long)b * 64 + t] = red[t] + red[64 + t] + red[128 + t] + red[192 + t] + bon2[0];
}

extern "C" void kernel_launch(void* const* d_in, const int* in_sizes, int n_in,
                              void* d_out, int out_size, void* d_ws, size_t ws_size,
                              hipStream_t stream) {
  (void)in_sizes; (void)n_in; (void)out_size;
  const float* input = (const float*)d_in[0];
  const float* W1    = (const float*)d_in[1];
  const float* b1    = (const float*)d_in[2];
  const float* W2    = (const float*)d_in[3];
  const float* b2    = (const float*)d_in[4];
  const float* Won1  = (const float*)d_in[5];
  const float* bon1  = (const float*)d_in[6];
  const float* Won2  = (const float*)d_in[7];
  const float* bon2  = (const float*)d_in[8];
  const float* Wc1   = (const float*)d_in[9];
  const float* bc1   = (const float*)d_in[10];
  const float* Wc2   = (const float*)d_in[11];
  const float* bc2   = (const float*)d_in[12];
  float* out = (float*)d_out;

  char* base = (char*)d_ws;
  unsigned short* inputb = (unsigned short*)(base);                  //   8 MB
  unsigned short* W1T    = (unsigned short*)(base + 8388608L);       //  32 MB [8][2048][1024]
  unsigned short* W2T    = (unsigned short*)(base + 41943040L);      //   8 MB [8][256][2048]
  unsigned short* WcatT  = (unsigned short*)(base + 50331648L);      //   2 MB [4096][256]
  unsigned short* Wc1T   = (unsigned short*)(base + 52428800L);      //   1 MB [2048][256]
  unsigned short* hbuf   = (unsigned short*)(base + 53477376L);      // 128 MB [8][4096][2048]
  unsigned short* embbuf = (unsigned short*)(base + 187695104L);     //  16 MB [8][4096][256]
  unsigned short* UVTbuf = (unsigned short*)(base + 204472320L);     // Mc*64KB [Mc][8][4096]

  int Mc = 512;
  const int mopts[3] = {4096, 2048, 1024};
  for (int oi = 0; oi < 3; ++oi) {
    if (204472320L + (long)mopts[oi] * 65536L <= (long)ws_size) { Mc = mopts[oi]; break; }
  }
  const int nc = 4096 / Mc;

  prep_kernel<<<dim3(24064), 256, 0, stream>>>(input, W1, W2, Won1, Wc1,
                                               inputb, W1T, W2T, WcatT, Wc1T);

  // G1 full-batch, 8-phase 256^2: h[k] = relu(input @ W1[k] + b1[k])
  gemm256<true, true><<<dim3(8 * 16 * 8), 512, 0, stream>>>(
      inputb, W1T, b1, hbuf, 2048, 1024, 2048, 8, 16, 4,
      0L, (long)2048 * 1024, 2048L, (long)4096 * 2048);

  // G2 full-batch, 8-phase 128x256 (fixed schedule): emb[k] = h[k] @ W2[k] + b2[k]
  gemm_bm128<true, false><<<dim3(256), 512, 0, stream>>>(
      hbuf, W2T, b2, embbuf, 256, 2048, 1, 32, 4,
      (long)4096 * 2048, (long)256 * 2048, 256L, (long)4096 * 256);

  // clear heads full-batch
  clear_fused<<<dim3(64, 8), 256, 0, stream>>>(embbuf, Wc1T, bc1, Wc2, bc2, out, 4096);

  // G3 (8-phase 256^2, K=256, b-major C) + pair reduce, chunked over b
  for (int cc = 0; cc < nc; ++cc) {
    const long b0 = (long)cc * Mc;
    const int nyc = Mc / 256;
    const int GM3 = (nyc % 4 == 0) ? 4 : ((nyc % 2 == 0) ? 2 : 1);
    gemm256<false, false><<<dim3(16 * nyc * 8), 512, 0, stream>>>(
        embbuf + b0 * 256, WcatT, nullptr, UVTbuf, 4096, 256, 32768, 16, nyc, GM3,
        (long)4096 * 256, 0L, 0L, 4096L);
    pair_reduce_kernel<<<dim3(Mc), 256, 0, stream>>>(
        UVTbuf, bon1, Won2, bon2, out + b0 * 64, Mc);
  }
}

// Round 13
// 521.257 us; speedup vs baseline: 1.4775x; 1.1184x over previous
//
#include <hip/hip_runtime.h>

typedef __attribute__((ext_vector_type(8))) short bf16x8;
typedef __attribute__((ext_vector_type(4))) float f32x4;
typedef __attribute__((ext_vector_type(8))) unsigned short u16x8;

__device__ __forceinline__ float bf2f(short s) {
  unsigned u = ((unsigned)(unsigned short)s) << 16;
  return __builtin_bit_cast(float, u);
}
__device__ __forceinline__ unsigned short f2bf(float f) {
  unsigned u = __builtin_bit_cast(unsigned, f);
  u = (u + 0x7fffu + ((u >> 16) & 1u)) >> 16;
  return (unsigned short)u;
}
__device__ __forceinline__ void gload16(const unsigned short* g, unsigned short* l) {
  __builtin_amdgcn_global_load_lds(
      (const __attribute__((address_space(1))) void*)g,
      (__attribute__((address_space(3))) void*)l, 16, 0, 0);
}

// ---------------- merged prep: input cvt + all 5 weight transposes ----------------
__global__ __launch_bounds__(256)
void prep_kernel(const float* __restrict__ input, const float* __restrict__ W1,
                 const float* __restrict__ W2, const float* __restrict__ Won1,
                 const float* __restrict__ Wc1,
                 unsigned short* __restrict__ inputb, unsigned short* __restrict__ W1T,
                 unsigned short* __restrict__ W2T, unsigned short* __restrict__ WcatT,
                 unsigned short* __restrict__ Wc1T) {
  int bid = blockIdx.x;
  const int t = threadIdx.x;
  if (bid < 2048) {  // cvt input -> bf16 (4096x1024)
    long i = ((long)bid * 256 + t) * 8;
    float4 a = *(const float4*)(input + i);
    float4 b = *(const float4*)(input + i + 4);
    u16x8 o;
    o[0] = f2bf(a.x); o[1] = f2bf(a.y); o[2] = f2bf(a.z); o[3] = f2bf(a.w);
    o[4] = f2bf(b.x); o[5] = f2bf(b.y); o[6] = f2bf(b.z); o[7] = f2bf(b.w);
    *(u16x8*)(inputb + i) = o;
    return;
  }
  bid -= 2048;
  const float* src; unsigned short* dst;
  int R, C, tilesX, tilesY; long sb, db;
  if (bid < 16384) {                    // W1[k][1024,2048] -> W1T[k][2048,1024]
    src = W1; dst = W1T; R = 1024; C = 2048; tilesX = 64; tilesY = 32;
    sb = 2097152; db = 2097152;
  } else if ((bid -= 16384) < 4096) {   // W2[k][2048,256] -> W2T[k][256,2048]
    src = W2; dst = W2T; R = 2048; C = 256; tilesX = 8; tilesY = 64;
    sb = 524288; db = 524288;
  } else if ((bid -= 4096) < 512) {     // Won1 top half -> WcatT rows 0..2047
    src = Won1; dst = WcatT; R = 256; C = 2048; tilesX = 64; tilesY = 8;
    sb = 0; db = 0;
  } else if ((bid -= 512) < 512) {      // Won1 bottom half -> WcatT rows 2048..4095
    src = Won1 + 524288; dst = WcatT + (long)2048 * 256;
    R = 256; C = 2048; tilesX = 64; tilesY = 8; sb = 0; db = 0;
  } else {                              // Wc1 -> Wc1T[2048,256]
    bid -= 512;
    src = Wc1; dst = Wc1T; R = 256; C = 2048; tilesX = 64; tilesY = 8;
    sb = 0; db = 0;
  }
  const int x = bid % tilesX;
  const int rem = bid / tilesX;
  const int y = rem % tilesY;
  const int z = rem / tilesY;
  src += (long)z * sb;
  dst += (long)z * db;
  __shared__ float tile[32][33];
  const int tx = t & 31, ty = t >> 5;
  const int bx = x * 32, by = y * 32;
  #pragma unroll
  for (int i = ty; i < 32; i += 8)
    tile[i][tx] = src[(long)(by + i) * C + bx + tx];
  __syncthreads();
  #pragma unroll
  for (int i = ty; i < 32; i += 8)
    dst[(long)(bx + i) * R + by + tx] = f2bf(tile[tx][i]);
}

// ---------------- 8-phase 256x256 GEMM (T2+T3+T4+T5): C = A[M,K] @ Bt[N,K]^T ----
// 512 threads, 8 waves (2M x 4N), BK=64. ldc = C row stride (b-major layouts).
// Stage-slot safety: every STAGE targets a region whose reads were drained by a
// CLOSED phase (lgkmcnt(0) + barrier) before the stage issues. Verified per-slot.
template<bool HAS_BIAS, bool RELU>
__global__ __launch_bounds__(512, 1)
void gemm256(const unsigned short* __restrict__ A,
             const unsigned short* __restrict__ Bt,
             const float* __restrict__ bias,
             unsigned short* __restrict__ C,
             int N, int K, int ldc, int nx, int ny, int GM,
             long sA, long sB, long sBias, long sC) {
  __shared__ unsigned short lds[65536];  // 128KB
  const int t = threadIdx.x;
  const int lane = t & 63;
  const int w = t >> 6, wr = w >> 2, wc = w & 3;

  const int nwg = gridDim.x;
  const int cpx = nwg >> 3;
  const int id = blockIdx.x;
  const int sw = (id & 7) * cpx + (id >> 3);
  const int z = sw / (nx * ny);
  const int rem = sw % (nx * ny);
  const int band = rem / (GM * nx);
  const int rr = rem % (GM * nx);
  const int y = band * GM + (rr % GM);
  const int x = rr / GM;
  const int m0 = y * 256, n0 = x * 256;

  A += (long)z * sA;
  Bt += (long)z * sB;
  C += (long)z * sC;

  const int NH = K >> 4;
  const int ITERS = K >> 7;

  const int sr0 = t >> 3;
  const int sc0 = (t & 7) * 16;
  const int cks0 = (((lane >> 4) * 16)) ^ ((lane & 7) << 4);
  const int cks1 = (64 + ((lane >> 4) * 16)) ^ ((lane & 7) << 4);
  const int aoff = wr * 16384 + (lane & 15) * 128;
  const int boff = 32768 + (wc >> 1) * 16384 + ((wc & 1) * 64 + (lane & 15)) * 128;

  f32x4 acc[8][4] = {};
  bf16x8 af[4][2];
  bf16x8 bfr[2][2][2];

#define STAGE(S) do { if ((S) < NH) {                                          \
    const int kt_ = (S) >> 2, slot_ = (S) & 3;                                 \
    const int base_ = ((kt_ & 1) << 16) + ((slot_ < 2) ? 32768 : 0)            \
                      + ((slot_ & 1) << 14);                                   \
    const unsigned short* gb_;                                                 \
    _Pragma("unroll")                                                          \
    for (int j_ = 0; j_ < 2; ++j_) {                                           \
      const int r_ = sr0 + j_ * 64;                                            \
      const int yc_ = sc0 ^ ((r_ & 7) << 4);                                   \
      if (slot_ < 2)                                                           \
        gb_ = Bt + (long)(n0 + (slot_ & 1) * 128 + r_) * K + kt_ * 64 + (yc_ >> 1); \
      else                                                                     \
        gb_ = A + (long)(m0 + (slot_ & 1) * 128 + r_) * K + kt_ * 64 + (yc_ >> 1);  \
      gload16(gb_, lds + (base_ >> 1) + j_ * 4096 + t * 8);                    \
    } } } while (0)

#define LDA_(BUF, HM) do { _Pragma("unroll")                                   \
    for (int mi_ = 0; mi_ < 4; ++mi_) {                                        \
      af[mi_][0] = *(const bf16x8*)((const char*)lds + (BUF) * 65536 + aoff + ((HM) * 4 + mi_) * 2048 + cks0); \
      af[mi_][1] = *(const bf16x8*)((const char*)lds + (BUF) * 65536 + aoff + ((HM) * 4 + mi_) * 2048 + cks1); \
    } } while (0)

#define LDB_(BUF, HN) do { _Pragma("unroll")                                   \
    for (int ni_ = 0; ni_ < 2; ++ni_) {                                        \
      bfr[HN][ni_][0] = *(const bf16x8*)((const char*)lds + (BUF) * 65536 + boff + ((HN) * 2 + ni_) * 2048 + cks0); \
      bfr[HN][ni_][1] = *(const bf16x8*)((const char*)lds + (BUF) * 65536 + boff + ((HN) * 2 + ni_) * 2048 + cks1); \
    } } while (0)

#define DO_MFMA(HM, HN) do { _Pragma("unroll")                                 \
    for (int mi_ = 0; mi_ < 4; ++mi_) { _Pragma("unroll")                      \
      for (int ni_ = 0; ni_ < 2; ++ni_) { _Pragma("unroll")                    \
        for (int ks_ = 0; ks_ < 2; ++ks_)                                      \
          acc[(HM) * 4 + mi_][(HN) * 2 + ni_] =                                \
            __builtin_amdgcn_mfma_f32_16x16x32_bf16(af[mi_][ks_], bfr[HN][ni_][ks_], \
                acc[(HM) * 4 + mi_][(HN) * 2 + ni_], 0, 0, 0);                 \
    } } } while (0)

#define PHASE(MB) do {                                                         \
    __builtin_amdgcn_s_barrier();                                              \
    asm volatile("s_waitcnt lgkmcnt(0)" ::: "memory");                         \
    __builtin_amdgcn_sched_barrier(0);                                         \
    __builtin_amdgcn_s_setprio(1);                                             \
    MB;                                                                        \
    __builtin_amdgcn_s_setprio(0);                                             \
    __builtin_amdgcn_s_barrier();                                              \
  } while (0)

  STAGE(0); STAGE(1); STAGE(2); STAGE(3);
  asm volatile("s_waitcnt vmcnt(4)" ::: "memory");
  STAGE(4); STAGE(5); STAGE(6);
  asm volatile("s_waitcnt vmcnt(6)" ::: "memory");
  __builtin_amdgcn_s_barrier();

  for (int i = 0; i < ITERS; ++i) {
    const int s0 = 7 + (i << 3);
    const bool last = (i == ITERS - 1);
    // ---- K-tile 2i (buf 0) ----
    LDA_(0, 0); LDB_(0, 0); STAGE(s0 + 0);
    asm volatile("s_waitcnt lgkmcnt(8)" ::: "memory");
    PHASE(DO_MFMA(0, 0));
    LDB_(0, 1);             STAGE(s0 + 1);
    PHASE(DO_MFMA(0, 1));
    LDA_(0, 1);             STAGE(s0 + 2);
    PHASE(DO_MFMA(1, 1));
                            STAGE(s0 + 3);
    if (last) asm volatile("s_waitcnt vmcnt(0)" ::: "memory");
    else      asm volatile("s_waitcnt vmcnt(6)" ::: "memory");
    PHASE(DO_MFMA(1, 0));
    // ---- K-tile 2i+1 (buf 1) ----
    LDA_(1, 0); LDB_(1, 0); STAGE(s0 + 4);
    asm volatile("s_waitcnt lgkmcnt(8)" ::: "memory");
    PHASE(DO_MFMA(0, 0));
    LDB_(1, 1);             STAGE(s0 + 5);
    PHASE(DO_MFMA(0, 1));
    LDA_(1, 1);             STAGE(s0 + 6);
    PHASE(DO_MFMA(1, 1));
                            STAGE(s0 + 7);
    if (!last) asm volatile("s_waitcnt vmcnt(6)" ::: "memory");
    PHASE(DO_MFMA(1, 0));
  }

#undef STAGE
#undef LDA_
#undef LDB_
#undef DO_MFMA
#undef PHASE

  #pragma unroll
  for (int Mi = 0; Mi < 8; ++Mi) {
    #pragma unroll
    for (int Ni = 0; Ni < 4; ++Ni) {
      const int colg = n0 + wc * 64 + Ni * 16 + (lane & 15);
      float bv = 0.f;
      if (HAS_BIAS) bv = bias[(long)z * sBias + colg];
      #pragma unroll
      for (int r2 = 0; r2 < 4; ++r2) {
        const int rowg = m0 + wr * 128 + Mi * 16 + (lane >> 4) * 4 + r2;
        float v = acc[Mi][Ni][r2] + bv;
        if (RELU) v = fmaxf(v, 0.f);
        C[(long)rowg * ldc + colg] = f2bf(v);
      }
    }
  }
}

// ---------------- 8-phase 128x256 GEMM (verified round-10 schedule) ----------------
template<bool HAS_BIAS, bool RELU>
__global__ __launch_bounds__(512, 1)
void gemm_bm128(const unsigned short* __restrict__ A,
                const unsigned short* __restrict__ Bt,
                const float* __restrict__ bias,
                unsigned short* __restrict__ C,
                int N, int K, int nx, int ny, int GM,
                long sA, long sB, long sBias, long sC) {
  __shared__ unsigned short lds[49152];  // 96KB
  const int t = threadIdx.x;
  const int lane = t & 63;
  const int w = t >> 6, wr = w >> 2, wc = w & 3;

  const int nwg = gridDim.x;
  const int cpx = nwg >> 3;
  const int id = blockIdx.x;
  const int sw = (id & 7) * cpx + (id >> 3);
  const int z = sw / (nx * ny);
  const int rem = sw % (nx * ny);
  const int band = rem / (GM * nx);
  const int rr = rem % (GM * nx);
  const int y = band * GM + (rr % GM);
  const int x = rr / GM;
  const int m0 = y * 128, n0 = x * 256;

  A += (long)z * sA;
  Bt += (long)z * sB;
  C += (long)z * sC;

  const int NH = K >> 4;
  const int ITERS = K >> 7;

  const int sr0 = t >> 3;
  const int sc0 = (t & 7) * 16;
  const int cks0 = (((lane >> 4) * 16)) ^ ((lane & 7) << 4);
  const int cks1 = (64 + ((lane >> 4) * 16)) ^ ((lane & 7) << 4);
  const int abase = 32768 + wr * 8192 + (lane & 15) * 128;
  const int bbase = (wc >> 1) * 16384 + ((wc & 1) * 64 + (lane & 15)) * 128;

  f32x4 acc[4][4] = {};
  bf16x8 af[4][2];
  bf16x8 bfr[2][2];

#define STAGE(S) do { if ((S) < NH) {                                          \
    const int kt_ = (S) >> 2, slot_ = (S) & 3;                                 \
    const int bufb_ = (kt_ & 1) * 49152;                                       \
    if (slot_ < 2) {                                                           \
      _Pragma("unroll")                                                        \
      for (int j_ = 0; j_ < 2; ++j_) {                                         \
        const int r_ = sr0 + j_ * 64;                                          \
        const int yc_ = sc0 ^ ((r_ & 7) << 4);                                 \
        gload16(Bt + (long)(n0 + slot_ * 128 + r_) * K + kt_ * 64 + (yc_ >> 1),\
                lds + ((bufb_ + slot_ * 16384 + j_ * 8192) >> 1) + t * 8);     \
      }                                                                        \
    } else {                                                                   \
      const int yc_ = sc0 ^ ((sr0 & 7) << 4);                                  \
      gload16(A + (long)(m0 + (slot_ & 1) * 64 + sr0) * K + kt_ * 64 + (yc_ >> 1), \
              lds + ((bufb_ + 32768 + (slot_ & 1) * 8192) >> 1) + t * 8);      \
    } } } while (0)

#define LDA_(BUF) do { _Pragma("unroll")                                       \
    for (int mi_ = 0; mi_ < 4; ++mi_) {                                        \
      af[mi_][0] = *(const bf16x8*)((const char*)lds + (BUF) * 49152 + abase + mi_ * 2048 + cks0); \
      af[mi_][1] = *(const bf16x8*)((const char*)lds + (BUF) * 49152 + abase + mi_ * 2048 + cks1); \
    } } while (0)

#define LDB_(BUF, HN) do { _Pragma("unroll")                                   \
    for (int ni_ = 0; ni_ < 2; ++ni_) {                                        \
      bfr[ni_][0] = *(const bf16x8*)((const char*)lds + (BUF) * 49152 + bbase + ((HN) * 2 + ni_) * 2048 + cks0); \
      bfr[ni_][1] = *(const bf16x8*)((const char*)lds + (BUF) * 49152 + bbase + ((HN) * 2 + ni_) * 2048 + cks1); \
    } } while (0)

#define DO_MFMA(HN) do { _Pragma("unroll")                                     \
    for (int mi_ = 0; mi_ < 4; ++mi_) { _Pragma("unroll")                      \
      for (int ni_ = 0; ni_ < 2; ++ni_) { _Pragma("unroll")                    \
        for (int ks_ = 0; ks_ < 2; ++ks_)                                      \
          acc[mi_][(HN) * 2 + ni_] =                                           \
            __builtin_amdgcn_mfma_f32_16x16x32_bf16(af[mi_][ks_], bfr[ni_][ks_], \
                acc[mi_][(HN) * 2 + ni_], 0, 0, 0);                            \
    } } } while (0)

#define PHASE(MB) do {                                                         \
    __builtin_amdgcn_s_barrier();                                              \
    asm volatile("s_waitcnt lgkmcnt(0)" ::: "memory");                         \
    __builtin_amdgcn_sched_barrier(0);                                         \
    __builtin_amdgcn_s_setprio(1);                                             \
    MB;                                                                        \
    __builtin_amdgcn_s_setprio(0);                                             \
    __builtin_amdgcn_s_barrier();                                              \
  } while (0)

  STAGE(0); STAGE(2); STAGE(3); STAGE(1);
  STAGE(4); STAGE(6); STAGE(7);
  asm volatile("s_waitcnt vmcnt(6)" ::: "memory");
  __builtin_amdgcn_s_barrier();

  for (int i = 0; i < ITERS; ++i) {
    const int s0 = i << 3;
    const bool last = (i == ITERS - 1);
    // ---- phase A: K-tile 2i (buf0), HN0 ----
    LDA_(0); LDB_(0, 0);
    STAGE(s0 + 5);
    asm volatile("s_waitcnt lgkmcnt(8)" ::: "memory");
    asm volatile("s_waitcnt vmcnt(6)" ::: "memory");
    PHASE(DO_MFMA(0));
    // ---- phase B: K-tile 2i, HN1 ----
    LDB_(0, 1);
    STAGE(s0 + 8); STAGE(s0 + 10); STAGE(s0 + 11);
    if (last) asm volatile("s_waitcnt vmcnt(0)" ::: "memory");
    else      asm volatile("s_waitcnt vmcnt(6)" ::: "memory");
    PHASE(DO_MFMA(1));
    // ---- phase C: K-tile 2i+1 (buf1), HN0 ----
    LDA_(1); LDB_(1, 0);
    STAGE(s0 + 9);
    asm volatile("s_waitcnt lgkmcnt(8)" ::: "memory");
    if (last) asm volatile("s_waitcnt vmcnt(0)" ::: "memory");
    else      asm volatile("s_waitcnt vmcnt(6)" ::: "memory");
    PHASE(DO_MFMA(0));
    // ---- phase D: K-tile 2i+1, HN1 ----
    LDB_(1, 1);
    STAGE(s0 + 12); STAGE(s0 + 14); STAGE(s0 + 15);
    if (!last) asm volatile("s_waitcnt vmcnt(6)" ::: "memory");
    PHASE(DO_MFMA(1));
  }

#undef STAGE
#undef LDA_
#undef LDB_
#undef DO_MFMA
#undef PHASE

  #pragma unroll
  for (int mi = 0; mi < 4; ++mi) {
    #pragma unroll
    for (int ni = 0; ni < 4; ++ni) {
      const int colg = n0 + wc * 64 + ni * 16 + (lane & 15);
      float bv = 0.f;
      if (HAS_BIAS) bv = bias[(long)z * sBias + colg];
      #pragma unroll
      for (int r2 = 0; r2 < 4; ++r2) {
        const int rowg = m0 + wr * 64 + mi * 16 + (lane >> 4) * 4 + r2;
        float v = acc[mi][ni][r2] + bv;
        if (RELU) v = fmaxf(v, 0.f);
        C[(long)rowg * N + colg] = f2bf(v);
      }
    }
  }
}

// ---------------- fused clear heads, 64-row blocks ----------------
__global__ __launch_bounds__(256, 3)
void clear_fused(const unsigned short* __restrict__ emb,   // [8][M][256]
                 const unsigned short* __restrict__ Wc1T,  // [2048][256]
                 const float* __restrict__ bc1, const float* __restrict__ Wc2,
                 const float* __restrict__ bc2,
                 float* __restrict__ out, int M) {
  __shared__ unsigned short Ae[64 * 256];
  __shared__ unsigned short Bs[128 * 64];
  __shared__ float red[4][64];
  const int t = threadIdx.x;
  const int lane = t & 63;
  const int w = t >> 6;
  const int k = blockIdx.y;
  const int m0 = blockIdx.x * 64;
  const unsigned short* A = emb + ((long)k * M + m0) * 256;

  #pragma unroll
  for (int pass = 0; pass < 8; ++pass) {
    const int row = pass * 8 + (t >> 5);
    const int sc = t & 31;
    float4 v = *(const float4*)(A + (long)row * 256 + sc * 8);
    *(float4*)((char*)Ae + row * 512 + ((sc * 16) ^ ((row & 7) << 4))) = v;
  }

  float rsum[4][4] = {};

  for (int nt = 0; nt < 16; ++nt) {
    f32x4 acc[4][2] = {};
    for (int kt = 0; kt < 256; kt += 64) {
      __syncthreads();
      #pragma unroll
      for (int pass = 0; pass < 4; ++pass) {
        const int row = pass * 32 + (t >> 3);
        gload16(Wc1T + (long)(nt * 128 + row) * 256 + kt + (t & 7) * 8,
                Bs + row * 64 + (t & 7) * 8);
      }
      __syncthreads();
      #pragma unroll
      for (int ks = 0; ks < 2; ++ks) {
        bf16x8 af[4], bfr[2];
        #pragma unroll
        for (int mi = 0; mi < 4; ++mi) {
          const int row = mi * 16 + (lane & 15);
          const int ce = kt + ks * 32 + (lane >> 4) * 8;
          af[mi] = *(const bf16x8*)((const char*)Ae + row * 512 + ((ce * 2) ^ ((row & 7) << 4)));
        }
        #pragma unroll
        for (int ni = 0; ni < 2; ++ni) {
          const int row = w * 32 + ni * 16 + (lane & 15);
          bfr[ni] = *(const bf16x8*)((const char*)Bs + row * 128 + ks * 64 + (lane >> 4) * 16);
        }
        #pragma unroll
        for (int mi = 0; mi < 4; ++mi)
          #pragma unroll
          for (int ni = 0; ni < 2; ++ni)
            acc[mi][ni] = __builtin_amdgcn_mfma_f32_16x16x32_bf16(af[mi], bfr[ni], acc[mi][ni], 0, 0, 0);
      }
    }
    #pragma unroll
    for (int mi = 0; mi < 4; ++mi) {
      #pragma unroll
      for (int ni = 0; ni < 2; ++ni) {
        const int col = nt * 128 + w * 32 + ni * 16 + (lane & 15);
        const float bv = bc1[col], wv = Wc2[col];
        #pragma unroll
        for (int r = 0; r < 4; ++r)
          rsum[mi][r] += fmaxf(acc[mi][ni][r] + bv, 0.f) * wv;
      }
    }
  }

  #pragma unroll
  for (int off = 1; off < 16; off <<= 1)
    #pragma unroll
    for (int mi = 0; mi < 4; ++mi)
      #pragma unroll
      for (int r = 0; r < 4; ++r)
        rsum[mi][r] += __shfl_xor(rsum[mi][r], off, 64);
  if ((lane & 15) == 0) {
    #pragma unroll
    for (int mi = 0; mi < 4; ++mi)
      #pragma unroll
      for (int r = 0; r < 4; ++r)
        red[w][mi * 16 + (lane >> 4) * 4 + r] = rsum[mi][r];
  }
  __syncthreads();
  if (t < 64)
    out[(long)(m0 + t) * 64 + 56 + k] =
        red[0][t] + red[1][t] + red[2][t] + red[3][t] + bc2[0];
}

// ---------------- pairwise reduce: on[p,b] ----------------
// UVT is b-major: [Mc][8][4096] -> one contiguous 64KB strip per b.
__global__ __launch_bounds__(256)
void pair_reduce_kernel(const unsigned short* __restrict__ UVT,
                        const float* __restrict__ bon1, const float* __restrict__ Won2,
                        const float* __restrict__ bon2,
                        float* __restrict__ out, int Mc) {
  __shared__ unsigned short uv[8 * 4096];
  const int b = blockIdx.x, t = threadIdx.x;
  const unsigned short* src = UVT + (long)b * 32768;

  float4 ba = *(const float4*)(bon1 + t * 8);
  float4 bb = *(const float4*)(bon1 + t * 8 + 4);
  const float bsv[8] = {ba.x, ba.y, ba.z, ba.w, bb.x, bb.y, bb.z, bb.w};

  for (int k = 0; k < 8; ++k) {
    const unsigned short* s = src + (long)k * 4096;
    {  // U half: raw copy
      const int c = t;
      const int byte = k * 8192 + ((c * 16) ^ ((k & 7) << 4));
      *(float4*)((char*)uv + byte) = *(const float4*)(s + c * 8);
    }
    {  // V half: add bon1, re-encode bf16
      const int c = 256 + t;
      bf16x8 v = *(const bf16x8*)(s + c * 8);
      u16x8 o;
      #pragma unroll
      for (int e = 0; e < 8; ++e)
        o[e] = f2bf(bf2f(v[e]) + bsv[e]);
      const int byte = k * 8192 + ((c * 16) ^ ((k & 7) << 4));
      *(u16x8*)((char*)uv + byte) = o;
    }
  }
  __syncthreads();
  const int p = t & 63, q = t >> 6;
  float acc = 0.f;
  if (p < 56) {
    const int i = p / 7;
    const int jj = p % 7;
    const int j = jj + (jj >= i);
    const char* ubase = (const char*)uv + i * 8192;
    const char* vbase = (const char*)uv + j * 8192;
    const int uswz = (i & 7) << 4, vswz = (j & 7) << 4;
    for (int it = 0; it < 64; ++it) {
      const int h = q * 512 + it * 8;
      bf16x8 uu = *(const bf16x8*)(ubase + ((h * 2) ^ uswz));
      bf16x8 vv = *(const bf16x8*)(vbase + ((4096 + h * 2) ^ vswz));
      float4 wa = *(const float4*)(Won2 + h);
      float4 wb = *(const float4*)(Won2 + h + 4);
      float wv[8] = {wa.x, wa.y, wa.z, wa.w, wb.x, wb.y, wb.z, wb.w};
      #pragma unroll
      for (int e = 0; e < 8; ++e) {
        float xv = bf2f(uu[e]) + bf2f(vv[e]);
        acc += fmaxf(xv, 0.f) * wv[e];
      }
    }
  }
  __syncthreads();
  float* red = (float*)uv;
  red[q * 64 + p] = acc;
  __syncthreads();
  if (t < 56)
    out[(long)b * 64 + t] = red[t] + red[64 + t] + red[128 + t] + red[192 + t] + bon2[0];
}

extern "C" void kernel_launch(void* const* d_in, const int* in_sizes, int n_in,
                              void* d_out, int out_size, void* d_ws, size_t ws_size,
                              hipStream_t stream) {
  (void)in_sizes; (void)n_in; (void)out_size; (void)ws_size;
  const float* input = (const float*)d_in[0];
  const float* W1    = (const float*)d_in[1];
  const float* b1    = (const float*)d_in[2];
  const float* W2    = (const float*)d_in[3];
  const float* b2    = (const float*)d_in[4];
  const float* Won1  = (const float*)d_in[5];
  const float* bon1  = (const float*)d_in[6];
  const float* Won2  = (const float*)d_in[7];
  const float* bon2  = (const float*)d_in[8];
  const float* Wc1   = (const float*)d_in[9];
  const float* bc1   = (const float*)d_in[10];
  const float* Wc2   = (const float*)d_in[11];
  const float* bc2   = (const float*)d_in[12];
  float* out = (float*)d_out;

  // Workspace layout (round-10 layout; ONLY change: UVT aliases hbuf, which is
  // dead after G2 — Mc=2048's UVT = 2048*64KB = 128MB = exactly hbuf's extent):
  //   inputb   0          (8 MB)
  //   W1T      8388608    (32 MB)  [8][2048][1024]
  //   W2T      41943040   (8 MB)   [8][256][2048]
  //   WcatT    50331648   (2 MB)   [4096][256]
  //   Wc1T     52428800   (1 MB)   [2048][256]
  //   hbuf     53477376   (128 MB) [8][4096][2048]  (dead after G2)
  //   UVT      53477376   (128 MB) [2048][8][4096]  (aliases hbuf)
  //   embbuf   187695104  (16 MB)  [8][4096][256]
  char* base = (char*)d_ws;
  unsigned short* inputb = (unsigned short*)(base);
  unsigned short* W1T    = (unsigned short*)(base + 8388608L);
  unsigned short* W2T    = (unsigned short*)(base + 41943040L);
  unsigned short* WcatT  = (unsigned short*)(base + 50331648L);
  unsigned short* Wc1T   = (unsigned short*)(base + 52428800L);
  unsigned short* hbuf   = (unsigned short*)(base + 53477376L);
  unsigned short* UVTbuf = hbuf;  // alias
  unsigned short* embbuf = (unsigned short*)(base + 187695104L);

  const int Mc = 2048;
  const int nc = 2;

  prep_kernel<<<dim3(24064), 256, 0, stream>>>(input, W1, W2, Won1, Wc1,
                                               inputb, W1T, W2T, WcatT, Wc1T);

  // G1 full-batch, 8-phase 256^2: h[k] = relu(input @ W1[k] + b1[k])
  gemm256<true, true><<<dim3(8 * 16 * 8), 512, 0, stream>>>(
      inputb, W1T, b1, hbuf, 2048, 1024, 2048, 8, 16, 4,
      0L, (long)2048 * 1024, 2048L, (long)4096 * 2048);

  // G2 full-batch, 8-phase 128x256: emb[k] = h[k] @ W2[k] + b2[k]
  gemm_bm128<true, false><<<dim3(256), 512, 0, stream>>>(
      hbuf, W2T, b2, embbuf, 256, 2048, 1, 32, 4,
      (long)4096 * 2048, (long)256 * 2048, 256L, (long)4096 * 256);

  // clear heads full-batch
  clear_fused<<<dim3(64, 8), 256, 0, stream>>>(embbuf, Wc1T, bc1, Wc2, bc2, out, 4096);

  // G3 (8-phase 256^2, K=256, b-major C into UVT alias) + pair reduce, chunked
  for (int cc = 0; cc < nc; ++cc) {
    const long b0 = (long)cc * Mc;
    const int nyc = Mc / 256;
    const int GM3 = (nyc % 4 == 0) ? 4 : ((nyc % 2 == 0) ? 2 : 1);
    gemm256<false, false><<<dim3(16 * nyc * 8), 512, 0, stream>>>(
        embbuf + b0 * 256, WcatT, nullptr, UVTbuf, 4096, 256, 32768, 16, nyc, GM3,
        (long)4096 * 256, 0L, 0L, 4096L);
    pair_reduce_kernel<<<dim3(Mc), 256, 0, stream>>>(
        UVTbuf, bon1, Won2, bon2, out + b0 * 64, Mc);
  }
}